// Round 2
// baseline (312.249 us; speedup 1.0000x reference)
//
#include <hip/hip_runtime.h>

#define B_ 2
#define S_ 2048
#define D_ 1024
#define H_ 16
#define DK_ 64
#define M_ (B_ * S_)   // 4096
#define N_ (3 * D_)    // 3072
#define KSPLIT 2
#define NT_ (S_ / 128 / KSPLIT)   // 8 K-tiles per block

typedef __bf16 bf16x8 __attribute__((ext_vector_type(8)));
typedef short s8vec __attribute__((ext_vector_type(8)));
typedef float f4vec __attribute__((ext_vector_type(4)));

static __device__ __forceinline__ ushort f2b(float f) {
  union { float f; unsigned u; } v; v.f = f;
  unsigned u = v.u;
  u += 0x7FFFu + ((u >> 16) & 1u);   // RNE to bf16
  return (ushort)(u >> 16);
}

static __device__ __forceinline__ unsigned pk2(float a, float b) {
#if __has_builtin(__builtin_amdgcn_cvt_pk_bf16_f32)
  typedef __bf16 b2 __attribute__((ext_vector_type(2)));
  b2 r = __builtin_amdgcn_cvt_pk_bf16_f32(a, b);
  return __builtin_bit_cast(unsigned, r);
#else
  return (unsigned)f2b(a) | ((unsigned)f2b(b) << 16);
#endif
}

static __device__ __forceinline__ float exp2f_fast(float x) {
#if __has_builtin(__builtin_amdgcn_exp2f)
  return __builtin_amdgcn_exp2f(x);
#else
  return __expf(x * 0.6931471805599453f);   // 2^x = e^(x ln2)
#endif
}

static __device__ __forceinline__ f4vec mfma16(s8vec a, s8vec b, f4vec c) {
  return __builtin_amdgcn_mfma_f32_16x16x32_bf16(
      __builtin_bit_cast(bf16x8, a), __builtin_bit_cast(bf16x8, b), c, 0, 0, 0);
}

static __device__ __forceinline__ void gl_lds16(const ushort* g, ushort* l) {
  __builtin_amdgcn_global_load_lds(
      (const __attribute__((address_space(1))) unsigned*)g,
      (__attribute__((address_space(3))) unsigned*)l, 16, 0, 0);
}

// raw workgroup barrier: drains LDS (lgkmcnt) only — in-flight GLOBAL loads to
// VGPRs stay outstanding across the barrier (the whole point of reg-prefetch).
// 0xC07F = vmcnt(63) expcnt(7) lgkmcnt(0). asm clobbers stop compiler reordering.
static __device__ __forceinline__ void wg_barrier_lds() {
  asm volatile("" ::: "memory");
  __builtin_amdgcn_s_waitcnt(0xC07F);
  __builtin_amdgcn_s_barrier();
  asm volatile("" ::: "memory");
}

// ---- fused input conversion: blocks [0,4096) convert x, [4096,4864) transpose W ----
// Wq (w==0) is pre-scaled by log2(e) so attn can use exp2 directly.
__global__ __launch_bounds__(256) void cvt_xw(const float* __restrict__ x,
                                              const float* __restrict__ Wq,
                                              const float* __restrict__ Wk,
                                              const float* __restrict__ Wv,
                                              ushort* __restrict__ xb,
                                              ushort* __restrict__ wbt) {
  __shared__ ushort T[64 * 72];
  const int t = threadIdx.x;
  if (blockIdx.x < 4096) {
    int i = blockIdx.x * 256 + t;
    float4 v = ((const float4*)x)[i];
    ushort4 o;
    o.x = f2b(v.x); o.y = f2b(v.y); o.z = f2b(v.z); o.w = f2b(v.w);
    ((ushort4*)xb)[i] = o;
    return;
  }
  const int r = blockIdx.x - 4096;                // 0..767
  const int w = r >> 8, h = (r >> 4) & 15, d0 = (r & 15) * 64;
  const float* W = (w == 0) ? Wq : (w == 1) ? Wk : Wv;
  const float sc = (w == 0) ? 1.4426950408889634f : 1.0f;
  const float* src = W + (size_t)h * 65536 + (size_t)d0 * 64;   // [64 d][64 k]
#pragma unroll
  for (int j = 0; j < 4; ++j) {
    int idx = j * 256 + t;
    int dr = idx >> 4, kc = (idx & 15) * 4;
    float4 v = *(const float4*)(src + dr * 64 + kc);
    T[(kc + 0) * 72 + dr] = f2b(v.x * sc);
    T[(kc + 1) * 72 + dr] = f2b(v.y * sc);
    T[(kc + 2) * 72 + dr] = f2b(v.z * sc);
    T[(kc + 3) * 72 + dr] = f2b(v.w * sc);
  }
  __syncthreads();
  const int kk = t >> 2, dcg = (t & 3) * 16;
  ushort* dst = wbt + ((size_t)w * 1024 + h * 64 + kk) * 1024 + d0 + dcg;
  *(s8vec*)dst       = *(const s8vec*)&T[kk * 72 + dcg];
  *(s8vec*)(dst + 8) = *(const s8vec*)&T[kk * 72 + dcg + 8];
}

// ---- fused QKV projection: C[4096][3072] = X[4096][1024] @ Wbt^T (m97 structure) ----
__global__ __launch_bounds__(256) void proj_gemm(const ushort* __restrict__ xb,
                                                 const ushort* __restrict__ wbt,
                                                 ushort* __restrict__ qkv) {
  __shared__ __attribute__((aligned(16))) ushort As[128 * 64];
  __shared__ __attribute__((aligned(16))) ushort Bs[128 * 64];
  const int tid = threadIdx.x, wid = tid >> 6, lane = tid & 63;
  const int quad = lane >> 4, l15 = lane & 15;
  const int wm = wid & 1, wn = wid >> 1;
  const int m0 = blockIdx.x * 128, n0 = blockIdx.y * 128;

  f4vec acc[4][4];
#pragma unroll
  for (int mb = 0; mb < 4; mb++)
#pragma unroll
    for (int nb = 0; nb < 4; nb++)
#pragma unroll
      for (int i = 0; i < 4; i++) acc[mb][nb][i] = 0.f;

  const int sr = tid >> 3, sg = tid & 7;
  const int lg = sg ^ (sr & 7);
  const ushort* Ab = xb + (size_t)m0 * D_;
  const ushort* Bb = wbt + (size_t)n0 * D_;

  for (int k0 = 0; k0 < D_; k0 += 64) {
    __syncthreads();
#pragma unroll
    for (int j = 0; j < 4; ++j) {
      int r = j * 32 + sr;
      gl_lds16(Ab + (size_t)r * D_ + k0 + lg * 8, &As[j * 2048 + wid * 512]);
      gl_lds16(Bb + (size_t)r * D_ + k0 + lg * 8, &Bs[j * 2048 + wid * 512]);
    }
    __syncthreads();

#pragma unroll
    for (int kb = 0; kb < 2; ++kb) {
      s8vec af[4], bf[4];
#pragma unroll
      for (int mb = 0; mb < 4; ++mb) {
        int m = wm * 64 + mb * 16 + l15;
        int gpos = (kb * 4 + quad) ^ (m & 7);
        af[mb] = *(const s8vec*)&As[m * 64 + gpos * 8];
      }
#pragma unroll
      for (int nb = 0; nb < 4; ++nb) {
        int n = wn * 64 + nb * 16 + l15;
        int gpos = (kb * 4 + quad) ^ (n & 7);
        bf[nb] = *(const s8vec*)&Bs[n * 64 + gpos * 8];
      }
#pragma unroll
      for (int mb = 0; mb < 4; ++mb)
#pragma unroll
        for (int nb = 0; nb < 4; ++nb)
          acc[mb][nb] = mfma16(af[mb], bf[nb], acc[mb][nb]);
    }
  }

  const size_t per = (size_t)B_ * H_ * S_ * DK_;
  const int w = n0 >> 10;
  if (w == 2) {
    ushort* vt = qkv + 2 * per;
#pragma unroll
    for (int mb = 0; mb < 4; ++mb)
#pragma unroll
      for (int nb = 0; nb < 4; ++nb)
#pragma unroll
        for (int i = 0; i < 4; ++i) {
          int m = m0 + wm * 64 + mb * 16 + quad * 4 + i;
          int b = m >> 11, s = m & 2047;
          int n1 = (n0 & 1023) + wn * 64 + nb * 16 + l15;
          vt[((size_t)b * 1024 + n1) * S_ + s] = f2b(acc[mb][nb][i]);
        }
  } else {
#pragma unroll
    for (int mb = 0; mb < 4; ++mb)
#pragma unroll
      for (int nb = 0; nb < 4; ++nb)
#pragma unroll
        for (int i = 0; i < 4; ++i) {
          int m = m0 + wm * 64 + mb * 16 + quad * 4 + i;
          int b = m >> 11, s = m & 2047;
          int n1 = (n0 & 1023) + wn * 64 + nb * 16 + l15;
          qkv[(size_t)w * per + (((size_t)b * H_ + (n1 >> 6)) * S_ + s) * 64 + (n1 & 63)] =
              f2b(acc[mb][nb][i]);
        }
  }
}

// ---- flash attention v5: KV-split=2 for occupancy. Grid (16,32,2): blockIdx.z
// selects key range [z*1024, z*1024+1024). 1024 blocks = 4/CU = 4 waves/SIMD
// (was 2 — latency-bound chain QK->exp2->permlane->PV needs wave overlap).
// No-max softmax => partials are additive: each half writes UNNORMALIZED O
// (z=0 -> out, z=1 -> op1 workspace) + per-row sum(exp) -> merged by `merge`.
// Per-wave structure identical to v4 (32 q-rows/wave, swapped QK^T, in-register
// P transpose via permlane32/16_swap, reg-prefetch double-buffered staging).
__global__ __launch_bounds__(256, 4) void attn(const ushort* __restrict__ qg,
                                               const ushort* __restrict__ kg,
                                               const ushort* __restrict__ vtg,
                                               float* __restrict__ out,
                                               float* __restrict__ op1,
                                               float* __restrict__ ls) {
  __shared__ __attribute__((aligned(16))) ushort Ks[128 * 64];     // [key][d] swizzled
  __shared__ __attribute__((aligned(16))) ushort Vt[2][64 * 64];   // [half][dv][key] swizzled
  const int qt = blockIdx.x, bh = blockIdx.y, z = blockIdx.z;
  const int b = bh >> 4, h = bh & 15;
  const int kt0 = z * NT_;
  const int tid = threadIdx.x, wid = tid >> 6, lane = tid & 63;
  const int quad = lane >> 4, l15 = lane & 15, l7 = l15 & 7;

  // Q B-fragments: 32 q-rows per wave (2 blocks of 16), loaded once.
  const ushort* qbase = qg + ((size_t)bh * S_ + qt * 128 + wid * 32) * DK_;
  s8vec bq[2][2];
#pragma unroll
  for (int qb = 0; qb < 2; ++qb)
#pragma unroll
    for (int kc = 0; kc < 2; ++kc)
      bq[qb][kc] = *(const s8vec*)(qbase + (size_t)(qb * 16 + l15) * DK_ + kc * 32 + quad * 8);

  f4vec o[4][2];            // O^T frags: [dv-block][q-block]
  float lsum[2] = {0.f, 0.f};
#pragma unroll
  for (int nb = 0; nb < 4; ++nb)
#pragma unroll
    for (int qb = 0; qb < 2; ++qb)
#pragma unroll
      for (int i = 0; i < 4; ++i) o[nb][qb][i] = 0.f;

  // staging: 256 threads stage 128x64 K + 64x128 V per tile.
  const int r5 = tid >> 3, gs = tid & 7;
  const int gk = gs ^ (r5 & 7);
  const ushort* kb_ = kg + (size_t)bh * S_ * DK_;
  const ushort* vb_ = vtg + (size_t)bh * 64 * S_;

  s8vec kr[4], vr[4];
#pragma unroll
  for (int j = 0; j < 4; ++j)
    kr[j] = *(const s8vec*)(kb_ + (size_t)(kt0 * 128 + j * 32 + r5) * DK_ + gk * 8);
#pragma unroll
  for (int jd = 0; jd < 2; ++jd)
#pragma unroll
    for (int hf = 0; hf < 2; ++hf)
      vr[jd * 2 + hf] =
          *(const s8vec*)(vb_ + (size_t)(jd * 32 + r5) * S_ + kt0 * 128 + hf * 64 + gk * 8);

  for (int kt = kt0; kt < kt0 + NT_; ++kt) {
    wg_barrier_lds();                       // readers of previous tile done
#pragma unroll
    for (int j = 0; j < 4; ++j)             // vmcnt auto-waits these regs
      *(s8vec*)&Ks[(j * 32 + r5) * 64 + gs * 8] = kr[j];
#pragma unroll
    for (int jd = 0; jd < 2; ++jd)
#pragma unroll
      for (int hf = 0; hf < 2; ++hf)
        *(s8vec*)&Vt[hf][(jd * 32 + r5) * 64 + gs * 8] = vr[jd * 2 + hf];
    if (kt + 1 < kt0 + NT_) {               // prefetch next tile; stays in flight
      const ushort* kn = kb_ + (size_t)(kt + 1) * 128 * DK_;
#pragma unroll
      for (int j = 0; j < 4; ++j)
        kr[j] = *(const s8vec*)(kn + (size_t)(j * 32 + r5) * DK_ + gk * 8);
      const ushort* vn = vb_ + (kt + 1) * 128;
#pragma unroll
      for (int jd = 0; jd < 2; ++jd)
#pragma unroll
        for (int hf = 0; hf < 2; ++hf)
          vr[jd * 2 + hf] = *(const s8vec*)(vn + (size_t)(jd * 32 + r5) * S_ + hf * 64 + gk * 8);
    }
    wg_barrier_lds();                       // staging writes visible

    // 4 chunks of 32 keys: QK^T (swapped) -> exp2 -> in-reg transpose -> PV
#pragma unroll
    for (int kc2 = 0; kc2 < 4; ++kc2) {
      s8vec ak[2][2];
#pragma unroll
      for (int kbs = 0; kbs < 2; ++kbs) {
        const int row = (kc2 * 2 + kbs) * 16 + l15;
        ak[kbs][0] = *(const s8vec*)&Ks[row * 64 + ((0 + quad) ^ l7) * 8];
        ak[kbs][1] = *(const s8vec*)&Ks[row * 64 + ((4 + quad) ^ l7) * 8];
      }
      const int half = kc2 >> 1, G = (kc2 & 1) * 4 + quad;
      s8vec av[4];
#pragma unroll
      for (int nb = 0; nb < 4; ++nb)
        av[nb] = *(const s8vec*)&Vt[half][(nb * 16 + l15) * 64 + (G ^ l7) * 8];

      f4vec st[2][2];   // S^T: [key-sub][q-block]; lane: key=sub*16+quad*4+i, q=l15
      __builtin_amdgcn_s_setprio(1);
#pragma unroll
      for (int kbs = 0; kbs < 2; ++kbs)
#pragma unroll
        for (int qb = 0; qb < 2; ++qb) {
          f4vec zz;
#pragma unroll
          for (int i = 0; i < 4; ++i) zz[i] = 0.f;
          zz = mfma16(ak[kbs][0], bq[qb][0], zz);
          st[kbs][qb] = mfma16(ak[kbs][1], bq[qb][1], zz);
        }
      __builtin_amdgcn_s_setprio(0);

#pragma unroll
      for (int qb = 0; qb < 2; ++qb) {
        float p0 = exp2f_fast(st[0][qb][0]), p1 = exp2f_fast(st[0][qb][1]);
        float p2 = exp2f_fast(st[0][qb][2]), p3 = exp2f_fast(st[0][qb][3]);
        float p4 = exp2f_fast(st[1][qb][0]), p5 = exp2f_fast(st[1][qb][1]);
        float p6 = exp2f_fast(st[1][qb][2]), p7 = exp2f_fast(st[1][qb][3]);
        lsum[qb] += ((p0 + p1) + (p2 + p3)) + ((p4 + p5) + (p6 + p7));
        // pack: wi = bf16 key-pairs {2q, 2q+1, 8+2q, 8+2q+1} (q = quad)
        unsigned w0 = pk2(p0, p1), w1 = pk2(p2, p3);
        unsigned w2 = pk2(p4, p5), w3 = pk2(p6, p7);
        // 2x2 reg-row transpose -> B-frag pairs {4q..4q+3}
        asm("v_permlane32_swap_b32 %0, %1" : "+v"(w0), "+v"(w2));
        asm("v_permlane16_swap_b32 %0, %1" : "+v"(w0), "+v"(w2));
        asm("v_permlane32_swap_b32 %0, %1" : "+v"(w1), "+v"(w3));
        asm("v_permlane16_swap_b32 %0, %1" : "+v"(w1), "+v"(w3));
        union { unsigned u[4]; s8vec v; } pb;
        pb.u[0] = w0; pb.u[1] = w1; pb.u[2] = w2; pb.u[3] = w3;
        __builtin_amdgcn_s_setprio(1);
#pragma unroll
        for (int nb = 0; nb < 4; ++nb) o[nb][qb] = mfma16(av[nb], pb.v, o[nb][qb]);
        __builtin_amdgcn_s_setprio(0);
      }
    }
  }

  // lsum: partial over this half's keys; reduce over quads -> full row partial.
  float lrow[2];
#pragma unroll
  for (int qb = 0; qb < 2; ++qb) {
    float s = lsum[qb];
    s += __shfl_xor(s, 16, 64);
    s += __shfl_xor(s, 32, 64);
    lrow[qb] = s;
  }
  if (lane < 16) {
#pragma unroll
    for (int qb = 0; qb < 2; ++qb)
      ls[(size_t)z * (B_ * H_ * S_) + (size_t)bh * S_ + qt * 128 + wid * 32 + qb * 16 + l15] =
          lrow[qb];
  }

  // UNNORMALIZED O^T[dv=nb*16+quad*4+i][q=qb*16+l15]
  if (z == 0) {
    float* ob = out + ((size_t)b * S_ + qt * 128 + wid * 32) * D_ + h * DK_;
#pragma unroll
    for (int qb = 0; qb < 2; ++qb)
#pragma unroll
      for (int nb = 0; nb < 4; ++nb) {
        float4 vvv;
        vvv.x = o[nb][qb][0]; vvv.y = o[nb][qb][1];
        vvv.z = o[nb][qb][2]; vvv.w = o[nb][qb][3];
        *(float4*)&ob[(size_t)(qb * 16 + l15) * D_ + nb * 16 + quad * 4] = vvv;
      }
  } else {
    float* ob = op1 + ((size_t)bh * S_ + qt * 128 + wid * 32) * 64;
#pragma unroll
    for (int qb = 0; qb < 2; ++qb)
#pragma unroll
      for (int nb = 0; nb < 4; ++nb) {
        float4 vvv;
        vvv.x = o[nb][qb][0]; vvv.y = o[nb][qb][1];
        vvv.z = o[nb][qb][2]; vvv.w = o[nb][qb][3];
        *(float4*)&ob[(size_t)(qb * 16 + l15) * 64 + nb * 16 + quad * 4] = vvv;
      }
  }
}

// ---- merge: out = (out + op1) / (l0 + l1), float4-vectorized ----
__global__ __launch_bounds__(256) void merge(float* __restrict__ out,
                                             const float* __restrict__ op1,
                                             const float* __restrict__ ls) {
  const int i = blockIdx.x * 256 + threadIdx.x;   // float4 index over B*S*D
  const int e = i * 4;
  const int d = e & (D_ - 1);
  const int s = (e >> 10) & (S_ - 1);
  const int b = e >> 21;
  const int bh = b * H_ + (d >> 6);
  const size_t row = (size_t)bh * S_ + s;
  const float l = ls[row] + ls[(size_t)(B_ * H_ * S_) + row];
  const float inv = 1.0f / l;
  float4 a = ((const float4*)out)[i];
  float4 c = ((const float4*)op1)[row * 16 + ((d & 63) >> 2)];
  a.x = (a.x + c.x) * inv;
  a.y = (a.y + c.y) * inv;
  a.z = (a.z + c.z) * inv;
  a.w = (a.w + c.w) * inv;
  ((float4*)out)[i] = a;
}

extern "C" void kernel_launch(void* const* d_in, const int* in_sizes, int n_in,
                              void* d_out, int out_size, void* d_ws, size_t ws_size,
                              hipStream_t stream) {
  const float* x  = (const float*)d_in[0];
  const float* Wq = (const float*)d_in[1];
  const float* Wk = (const float*)d_in[2];
  const float* Wv = (const float*)d_in[3];
  float* out = (float*)d_out;

  ushort* xb  = (ushort*)d_ws;                       // B*S*D bf16
  ushort* wbt = xb + (size_t)B_ * S_ * D_;           // [3072][1024] bf16
  ushort* qkv = wbt + (size_t)3 * D_ * D_;           // q,k: [b][h][s][64]; v: [b*1024+n1][s]
  const size_t per = (size_t)B_ * H_ * S_ * DK_;
  float* ls  = (float*)(qkv + 3 * per);              // [2][B*H*S] sum(exp)
  float* op1 = ls + (size_t)2 * B_ * H_ * S_;        // [B*H][S][64] half-1 partial O

  cvt_xw<<<4096 + 768, 256, 0, stream>>>(x, Wq, Wk, Wv, xb, wbt);
  proj_gemm<<<dim3(M_ / 128, N_ / 128), 256, 0, stream>>>(xb, wbt, qkv);
  attn<<<dim3(S_ / 128, B_ * H_, KSPLIT), 256, 0, stream>>>(qkv, qkv + per, qkv + 2 * per,
                                                            out, op1, ls);
  merge<<<(B_ * S_ * D_) / 4 / 256, 256, 0, stream>>>(out, op1, ls);
}

// Round 3
// 187.763 us; speedup vs baseline: 1.6630x; 1.6630x over previous
//
#include <hip/hip_runtime.h>

#define B_ 2
#define S_ 2048
#define D_ 1024
#define H_ 16
#define DK_ 64
#define M_ (B_ * S_)   // 4096
#define N_ (3 * D_)    // 3072
#define KSPLIT 2
#define NT_ (S_ / 128 / KSPLIT)   // 8 K-tiles per block

typedef __bf16 bf16x8 __attribute__((ext_vector_type(8)));
typedef short s8vec __attribute__((ext_vector_type(8)));
typedef float f4vec __attribute__((ext_vector_type(4)));

static __device__ __forceinline__ ushort f2b(float f) {
  union { float f; unsigned u; } v; v.f = f;
  unsigned u = v.u;
  u += 0x7FFFu + ((u >> 16) & 1u);   // RNE to bf16
  return (ushort)(u >> 16);
}

static __device__ __forceinline__ unsigned pk2(float a, float b) {
#if __has_builtin(__builtin_amdgcn_cvt_pk_bf16_f32)
  typedef __bf16 b2 __attribute__((ext_vector_type(2)));
  b2 r = __builtin_amdgcn_cvt_pk_bf16_f32(a, b);
  return __builtin_bit_cast(unsigned, r);
#else
  return (unsigned)f2b(a) | ((unsigned)f2b(b) << 16);
#endif
}

static __device__ __forceinline__ float exp2f_fast(float x) {
#if __has_builtin(__builtin_amdgcn_exp2f)
  return __builtin_amdgcn_exp2f(x);
#else
  return __expf(x * 0.6931471805599453f);   // 2^x = e^(x ln2)
#endif
}

static __device__ __forceinline__ f4vec mfma16(s8vec a, s8vec b, f4vec c) {
  return __builtin_amdgcn_mfma_f32_16x16x32_bf16(
      __builtin_bit_cast(bf16x8, a), __builtin_bit_cast(bf16x8, b), c, 0, 0, 0);
}

static __device__ __forceinline__ void gl_lds16(const ushort* g, ushort* l) {
  __builtin_amdgcn_global_load_lds(
      (const __attribute__((address_space(1))) unsigned*)g,
      (__attribute__((address_space(3))) unsigned*)l, 16, 0, 0);
}

// raw workgroup barrier: drains LDS (lgkmcnt) only — in-flight GLOBAL loads to
// VGPRs stay outstanding across the barrier (the whole point of reg-prefetch).
// 0xC07F = vmcnt(63) expcnt(7) lgkmcnt(0). asm clobbers stop compiler reordering.
static __device__ __forceinline__ void wg_barrier_lds() {
  asm volatile("" ::: "memory");
  __builtin_amdgcn_s_waitcnt(0xC07F);
  __builtin_amdgcn_s_barrier();
  asm volatile("" ::: "memory");
}

// ---- fused input conversion: blocks [0,4096) convert x, [4096,4864) transpose W ----
// Wq (w==0) is pre-scaled by log2(e) so attn can use exp2 directly.
__global__ __launch_bounds__(256) void cvt_xw(const float* __restrict__ x,
                                              const float* __restrict__ Wq,
                                              const float* __restrict__ Wk,
                                              const float* __restrict__ Wv,
                                              ushort* __restrict__ xb,
                                              ushort* __restrict__ wbt) {
  __shared__ ushort T[64 * 72];
  const int t = threadIdx.x;
  if (blockIdx.x < 4096) {
    int i = blockIdx.x * 256 + t;
    float4 v = ((const float4*)x)[i];
    ushort4 o;
    o.x = f2b(v.x); o.y = f2b(v.y); o.z = f2b(v.z); o.w = f2b(v.w);
    ((ushort4*)xb)[i] = o;
    return;
  }
  const int r = blockIdx.x - 4096;                // 0..767
  const int w = r >> 8, h = (r >> 4) & 15, d0 = (r & 15) * 64;
  const float* W = (w == 0) ? Wq : (w == 1) ? Wk : Wv;
  const float sc = (w == 0) ? 1.4426950408889634f : 1.0f;
  const float* src = W + (size_t)h * 65536 + (size_t)d0 * 64;   // [64 d][64 k]
#pragma unroll
  for (int j = 0; j < 4; ++j) {
    int idx = j * 256 + t;
    int dr = idx >> 4, kc = (idx & 15) * 4;
    float4 v = *(const float4*)(src + dr * 64 + kc);
    T[(kc + 0) * 72 + dr] = f2b(v.x * sc);
    T[(kc + 1) * 72 + dr] = f2b(v.y * sc);
    T[(kc + 2) * 72 + dr] = f2b(v.z * sc);
    T[(kc + 3) * 72 + dr] = f2b(v.w * sc);
  }
  __syncthreads();
  const int kk = t >> 2, dcg = (t & 3) * 16;
  ushort* dst = wbt + ((size_t)w * 1024 + h * 64 + kk) * 1024 + d0 + dcg;
  *(s8vec*)dst       = *(const s8vec*)&T[kk * 72 + dcg];
  *(s8vec*)(dst + 8) = *(const s8vec*)&T[kk * 72 + dcg + 8];
}

// ---- fused QKV projection: C[4096][3072] = X[4096][1024] @ Wbt^T (m97 structure) ----
__global__ __launch_bounds__(256) void proj_gemm(const ushort* __restrict__ xb,
                                                 const ushort* __restrict__ wbt,
                                                 ushort* __restrict__ qkv) {
  __shared__ __attribute__((aligned(16))) ushort As[128 * 64];
  __shared__ __attribute__((aligned(16))) ushort Bs[128 * 64];
  const int tid = threadIdx.x, wid = tid >> 6, lane = tid & 63;
  const int quad = lane >> 4, l15 = lane & 15;
  const int wm = wid & 1, wn = wid >> 1;
  const int m0 = blockIdx.x * 128, n0 = blockIdx.y * 128;

  f4vec acc[4][4];
#pragma unroll
  for (int mb = 0; mb < 4; mb++)
#pragma unroll
    for (int nb = 0; nb < 4; nb++)
#pragma unroll
      for (int i = 0; i < 4; i++) acc[mb][nb][i] = 0.f;

  const int sr = tid >> 3, sg = tid & 7;
  const int lg = sg ^ (sr & 7);
  const ushort* Ab = xb + (size_t)m0 * D_;
  const ushort* Bb = wbt + (size_t)n0 * D_;

  for (int k0 = 0; k0 < D_; k0 += 64) {
    __syncthreads();
#pragma unroll
    for (int j = 0; j < 4; ++j) {
      int r = j * 32 + sr;
      gl_lds16(Ab + (size_t)r * D_ + k0 + lg * 8, &As[j * 2048 + wid * 512]);
      gl_lds16(Bb + (size_t)r * D_ + k0 + lg * 8, &Bs[j * 2048 + wid * 512]);
    }
    __syncthreads();

#pragma unroll
    for (int kb = 0; kb < 2; ++kb) {
      s8vec af[4], bf[4];
#pragma unroll
      for (int mb = 0; mb < 4; ++mb) {
        int m = wm * 64 + mb * 16 + l15;
        int gpos = (kb * 4 + quad) ^ (m & 7);
        af[mb] = *(const s8vec*)&As[m * 64 + gpos * 8];
      }
#pragma unroll
      for (int nb = 0; nb < 4; ++nb) {
        int n = wn * 64 + nb * 16 + l15;
        int gpos = (kb * 4 + quad) ^ (n & 7);
        bf[nb] = *(const s8vec*)&Bs[n * 64 + gpos * 8];
      }
#pragma unroll
      for (int mb = 0; mb < 4; ++mb)
#pragma unroll
        for (int nb = 0; nb < 4; ++nb)
          acc[mb][nb] = mfma16(af[mb], bf[nb], acc[mb][nb]);
    }
  }

  const size_t per = (size_t)B_ * H_ * S_ * DK_;
  const int w = n0 >> 10;
  if (w == 2) {
    ushort* vt = qkv + 2 * per;
#pragma unroll
    for (int mb = 0; mb < 4; ++mb)
#pragma unroll
      for (int nb = 0; nb < 4; ++nb)
#pragma unroll
        for (int i = 0; i < 4; ++i) {
          int m = m0 + wm * 64 + mb * 16 + quad * 4 + i;
          int b = m >> 11, s = m & 2047;
          int n1 = (n0 & 1023) + wn * 64 + nb * 16 + l15;
          vt[((size_t)b * 1024 + n1) * S_ + s] = f2b(acc[mb][nb][i]);
        }
  } else {
#pragma unroll
    for (int mb = 0; mb < 4; ++mb)
#pragma unroll
      for (int nb = 0; nb < 4; ++nb)
#pragma unroll
        for (int i = 0; i < 4; ++i) {
          int m = m0 + wm * 64 + mb * 16 + quad * 4 + i;
          int b = m >> 11, s = m & 2047;
          int n1 = (n0 & 1023) + wn * 64 + nb * 16 + l15;
          qkv[(size_t)w * per + (((size_t)b * H_ + (n1 >> 6)) * S_ + s) * 64 + (n1 & 63)] =
              f2b(acc[mb][nb][i]);
        }
  }
}

// ---- flash attention v6: KV-split=2 for occupancy, NO min-waves clamp.
// v5's __launch_bounds__(256,4) clamped VGPR to 64 -> accumulator spills
// (483 MB scratch writes, MfmaUtil 7%). Natural allocation (~100 VGPR <= 128)
// already permits 4 waves/SIMD; let the allocator have it.
// Grid (16,32,2): blockIdx.z selects key range. 1024 blocks = 4 blocks/CU.
// No-max softmax => partials additive: unnormalized O (z=0 -> out, z=1 -> op1)
// + per-row sum(exp) -> merged by `merge`.
__global__ __launch_bounds__(256) void attn(const ushort* __restrict__ qg,
                                            const ushort* __restrict__ kg,
                                            const ushort* __restrict__ vtg,
                                            float* __restrict__ out,
                                            float* __restrict__ op1,
                                            float* __restrict__ ls) {
  __shared__ __attribute__((aligned(16))) ushort Ks[128 * 64];     // [key][d] swizzled
  __shared__ __attribute__((aligned(16))) ushort Vt[2][64 * 64];   // [half][dv][key] swizzled
  const int qt = blockIdx.x, bh = blockIdx.y, z = blockIdx.z;
  const int b = bh >> 4, h = bh & 15;
  const int kt0 = z * NT_;
  const int tid = threadIdx.x, wid = tid >> 6, lane = tid & 63;
  const int quad = lane >> 4, l15 = lane & 15, l7 = l15 & 7;

  // Q B-fragments: 32 q-rows per wave (2 blocks of 16), loaded once.
  const ushort* qbase = qg + ((size_t)bh * S_ + qt * 128 + wid * 32) * DK_;
  s8vec bq[2][2];
#pragma unroll
  for (int qb = 0; qb < 2; ++qb)
#pragma unroll
    for (int kc = 0; kc < 2; ++kc)
      bq[qb][kc] = *(const s8vec*)(qbase + (size_t)(qb * 16 + l15) * DK_ + kc * 32 + quad * 8);

  f4vec o[4][2];            // O^T frags: [dv-block][q-block]
  float lsum[2] = {0.f, 0.f};
#pragma unroll
  for (int nb = 0; nb < 4; ++nb)
#pragma unroll
    for (int qb = 0; qb < 2; ++qb)
#pragma unroll
      for (int i = 0; i < 4; ++i) o[nb][qb][i] = 0.f;

  // staging: 256 threads stage 128x64 K + 64x128 V per tile.
  const int r5 = tid >> 3, gs = tid & 7;
  const int gk = gs ^ (r5 & 7);
  const ushort* kb_ = kg + (size_t)bh * S_ * DK_;
  const ushort* vb_ = vtg + (size_t)bh * 64 * S_;

  s8vec kr[4], vr[4];
#pragma unroll
  for (int j = 0; j < 4; ++j)
    kr[j] = *(const s8vec*)(kb_ + (size_t)(kt0 * 128 + j * 32 + r5) * DK_ + gk * 8);
#pragma unroll
  for (int jd = 0; jd < 2; ++jd)
#pragma unroll
    for (int hf = 0; hf < 2; ++hf)
      vr[jd * 2 + hf] =
          *(const s8vec*)(vb_ + (size_t)(jd * 32 + r5) * S_ + kt0 * 128 + hf * 64 + gk * 8);

  for (int kt = kt0; kt < kt0 + NT_; ++kt) {
    wg_barrier_lds();                       // readers of previous tile done
#pragma unroll
    for (int j = 0; j < 4; ++j)             // vmcnt auto-waits these regs
      *(s8vec*)&Ks[(j * 32 + r5) * 64 + gs * 8] = kr[j];
#pragma unroll
    for (int jd = 0; jd < 2; ++jd)
#pragma unroll
      for (int hf = 0; hf < 2; ++hf)
        *(s8vec*)&Vt[hf][(jd * 32 + r5) * 64 + gs * 8] = vr[jd * 2 + hf];
    if (kt + 1 < kt0 + NT_) {               // prefetch next tile; stays in flight
      const ushort* kn = kb_ + (size_t)(kt + 1) * 128 * DK_;
#pragma unroll
      for (int j = 0; j < 4; ++j)
        kr[j] = *(const s8vec*)(kn + (size_t)(j * 32 + r5) * DK_ + gk * 8);
      const ushort* vn = vb_ + (kt + 1) * 128;
#pragma unroll
      for (int jd = 0; jd < 2; ++jd)
#pragma unroll
        for (int hf = 0; hf < 2; ++hf)
          vr[jd * 2 + hf] = *(const s8vec*)(vn + (size_t)(jd * 32 + r5) * S_ + hf * 64 + gk * 8);
    }
    wg_barrier_lds();                       // staging writes visible

    // 4 chunks of 32 keys: QK^T (swapped) -> exp2 -> in-reg transpose -> PV
#pragma unroll
    for (int kc2 = 0; kc2 < 4; ++kc2) {
      s8vec ak[2][2];
#pragma unroll
      for (int kbs = 0; kbs < 2; ++kbs) {
        const int row = (kc2 * 2 + kbs) * 16 + l15;
        ak[kbs][0] = *(const s8vec*)&Ks[row * 64 + ((0 + quad) ^ l7) * 8];
        ak[kbs][1] = *(const s8vec*)&Ks[row * 64 + ((4 + quad) ^ l7) * 8];
      }
      const int half = kc2 >> 1, G = (kc2 & 1) * 4 + quad;
      s8vec av[4];
#pragma unroll
      for (int nb = 0; nb < 4; ++nb)
        av[nb] = *(const s8vec*)&Vt[half][(nb * 16 + l15) * 64 + (G ^ l7) * 8];

      f4vec st[2][2];   // S^T: [key-sub][q-block]; lane: key=sub*16+quad*4+i, q=l15
      __builtin_amdgcn_s_setprio(1);
#pragma unroll
      for (int kbs = 0; kbs < 2; ++kbs)
#pragma unroll
        for (int qb = 0; qb < 2; ++qb) {
          f4vec zz;
#pragma unroll
          for (int i = 0; i < 4; ++i) zz[i] = 0.f;
          zz = mfma16(ak[kbs][0], bq[qb][0], zz);
          st[kbs][qb] = mfma16(ak[kbs][1], bq[qb][1], zz);
        }
      __builtin_amdgcn_s_setprio(0);

#pragma unroll
      for (int qb = 0; qb < 2; ++qb) {
        float p0 = exp2f_fast(st[0][qb][0]), p1 = exp2f_fast(st[0][qb][1]);
        float p2 = exp2f_fast(st[0][qb][2]), p3 = exp2f_fast(st[0][qb][3]);
        float p4 = exp2f_fast(st[1][qb][0]), p5 = exp2f_fast(st[1][qb][1]);
        float p6 = exp2f_fast(st[1][qb][2]), p7 = exp2f_fast(st[1][qb][3]);
        lsum[qb] += ((p0 + p1) + (p2 + p3)) + ((p4 + p5) + (p6 + p7));
        // pack: wi = bf16 key-pairs {2q, 2q+1, 8+2q, 8+2q+1} (q = quad)
        unsigned w0 = pk2(p0, p1), w1 = pk2(p2, p3);
        unsigned w2 = pk2(p4, p5), w3 = pk2(p6, p7);
        // 2x2 reg-row transpose -> B-frag pairs {4q..4q+3}
        asm("v_permlane32_swap_b32 %0, %1" : "+v"(w0), "+v"(w2));
        asm("v_permlane16_swap_b32 %0, %1" : "+v"(w0), "+v"(w2));
        asm("v_permlane32_swap_b32 %0, %1" : "+v"(w1), "+v"(w3));
        asm("v_permlane16_swap_b32 %0, %1" : "+v"(w1), "+v"(w3));
        union { unsigned u[4]; s8vec v; } pb;
        pb.u[0] = w0; pb.u[1] = w1; pb.u[2] = w2; pb.u[3] = w3;
        __builtin_amdgcn_s_setprio(1);
#pragma unroll
        for (int nb = 0; nb < 4; ++nb) o[nb][qb] = mfma16(av[nb], pb.v, o[nb][qb]);
        __builtin_amdgcn_s_setprio(0);
      }
    }
  }

  // lsum: partial over this half's keys; reduce over quads -> full row partial.
  float lrow[2];
#pragma unroll
  for (int qb = 0; qb < 2; ++qb) {
    float s = lsum[qb];
    s += __shfl_xor(s, 16, 64);
    s += __shfl_xor(s, 32, 64);
    lrow[qb] = s;
  }
  if (lane < 16) {
#pragma unroll
    for (int qb = 0; qb < 2; ++qb)
      ls[(size_t)z * (B_ * H_ * S_) + (size_t)bh * S_ + qt * 128 + wid * 32 + qb * 16 + l15] =
          lrow[qb];
  }

  // UNNORMALIZED O^T[dv=nb*16+quad*4+i][q=qb*16+l15]
  if (z == 0) {
    float* ob = out + ((size_t)b * S_ + qt * 128 + wid * 32) * D_ + h * DK_;
#pragma unroll
    for (int qb = 0; qb < 2; ++qb)
#pragma unroll
      for (int nb = 0; nb < 4; ++nb) {
        float4 vvv;
        vvv.x = o[nb][qb][0]; vvv.y = o[nb][qb][1];
        vvv.z = o[nb][qb][2]; vvv.w = o[nb][qb][3];
        *(float4*)&ob[(size_t)(qb * 16 + l15) * D_ + nb * 16 + quad * 4] = vvv;
      }
  } else {
    float* ob = op1 + ((size_t)bh * S_ + qt * 128 + wid * 32) * 64;
#pragma unroll
    for (int qb = 0; qb < 2; ++qb)
#pragma unroll
      for (int nb = 0; nb < 4; ++nb) {
        float4 vvv;
        vvv.x = o[nb][qb][0]; vvv.y = o[nb][qb][1];
        vvv.z = o[nb][qb][2]; vvv.w = o[nb][qb][3];
        *(float4*)&ob[(size_t)(qb * 16 + l15) * 64 + nb * 16 + quad * 4] = vvv;
      }
  }
}

// ---- merge: out = (out + op1) / (l0 + l1), float4-vectorized ----
__global__ __launch_bounds__(256) void merge(float* __restrict__ out,
                                             const float* __restrict__ op1,
                                             const float* __restrict__ ls) {
  const int i = blockIdx.x * 256 + threadIdx.x;   // float4 index over B*S*D
  const int e = i * 4;
  const int d = e & (D_ - 1);
  const int s = (e >> 10) & (S_ - 1);
  const int b = e >> 21;
  const int bh = b * H_ + (d >> 6);
  const size_t row = (size_t)bh * S_ + s;
  const float l = ls[row] + ls[(size_t)(B_ * H_ * S_) + row];
  const float inv = 1.0f / l;
  float4 a = ((const float4*)out)[i];
  float4 c = ((const float4*)op1)[row * 16 + ((d & 63) >> 2)];
  a.x = (a.x + c.x) * inv;
  a.y = (a.y + c.y) * inv;
  a.z = (a.z + c.z) * inv;
  a.w = (a.w + c.w) * inv;
  ((float4*)out)[i] = a;
}

extern "C" void kernel_launch(void* const* d_in, const int* in_sizes, int n_in,
                              void* d_out, int out_size, void* d_ws, size_t ws_size,
                              hipStream_t stream) {
  const float* x  = (const float*)d_in[0];
  const float* Wq = (const float*)d_in[1];
  const float* Wk = (const float*)d_in[2];
  const float* Wv = (const float*)d_in[3];
  float* out = (float*)d_out;

  ushort* xb  = (ushort*)d_ws;                       // B*S*D bf16
  ushort* wbt = xb + (size_t)B_ * S_ * D_;           // [3072][1024] bf16
  ushort* qkv = wbt + (size_t)3 * D_ * D_;           // q,k: [b][h][s][64]; v: [b*1024+n1][s]
  const size_t per = (size_t)B_ * H_ * S_ * DK_;
  float* ls  = (float*)(qkv + 3 * per);              // [2][B*H*S] sum(exp)
  float* op1 = ls + (size_t)2 * B_ * H_ * S_;        // [B*H][S][64] half-1 partial O

  cvt_xw<<<4096 + 768, 256, 0, stream>>>(x, Wq, Wk, Wv, xb, wbt);
  proj_gemm<<<dim3(M_ / 128, N_ / 128), 256, 0, stream>>>(xb, wbt, qkv);
  attn<<<dim3(S_ / 128, B_ * H_, KSPLIT), 256, 0, stream>>>(qkv, qkv + per, qkv + 2 * per,
                                                            out, op1, ls);
  merge<<<(B_ * S_ * D_) / 4 / 256, 256, 0, stream>>>(out, op1, ls);
}

// Round 4
// 174.790 us; speedup vs baseline: 1.7864x; 1.0742x over previous
//
#include <hip/hip_runtime.h>

#define B_ 2
#define S_ 2048
#define D_ 1024
#define H_ 16
#define DK_ 64
#define M_ (B_ * S_)   // 4096
#define N_ (3 * D_)    // 3072

typedef __bf16 bf16x8 __attribute__((ext_vector_type(8)));
typedef short s8vec __attribute__((ext_vector_type(8)));
typedef float f4vec __attribute__((ext_vector_type(4)));

static __device__ __forceinline__ ushort f2b(float f) {
  union { float f; unsigned u; } v; v.f = f;
  unsigned u = v.u;
  u += 0x7FFFu + ((u >> 16) & 1u);   // RNE to bf16
  return (ushort)(u >> 16);
}

static __device__ __forceinline__ unsigned pk2(float a, float b) {
#if __has_builtin(__builtin_amdgcn_cvt_pk_bf16_f32)
  typedef __bf16 b2 __attribute__((ext_vector_type(2)));
  b2 r = __builtin_amdgcn_cvt_pk_bf16_f32(a, b);
  return __builtin_bit_cast(unsigned, r);
#else
  return (unsigned)f2b(a) | ((unsigned)f2b(b) << 16);
#endif
}

static __device__ __forceinline__ float exp2f_fast(float x) {
#if __has_builtin(__builtin_amdgcn_exp2f)
  return __builtin_amdgcn_exp2f(x);
#else
  return __expf(x * 0.6931471805599453f);   // 2^x = e^(x ln2)
#endif
}

static __device__ __forceinline__ f4vec mfma16(s8vec a, s8vec b, f4vec c) {
  return __builtin_amdgcn_mfma_f32_16x16x32_bf16(
      __builtin_bit_cast(bf16x8, a), __builtin_bit_cast(bf16x8, b), c, 0, 0, 0);
}

static __device__ __forceinline__ void gl_lds16(const ushort* g, ushort* l) {
  __builtin_amdgcn_global_load_lds(
      (const __attribute__((address_space(1))) unsigned*)g,
      (__attribute__((address_space(3))) unsigned*)l, 16, 0, 0);
}

// raw workgroup barrier: drains LDS (lgkmcnt) only — in-flight GLOBAL loads to
// VGPRs stay outstanding across the barrier (the whole point of reg-prefetch).
// 0xC07F = vmcnt(63) expcnt(7) lgkmcnt(0). asm clobbers stop compiler reordering.
static __device__ __forceinline__ void wg_barrier_lds() {
  asm volatile("" ::: "memory");
  __builtin_amdgcn_s_waitcnt(0xC07F);
  __builtin_amdgcn_s_barrier();
  asm volatile("" ::: "memory");
}

// ---- fused input conversion: blocks [0,4096) convert x, [4096,4864) transpose W ----
// Wq (w==0) is pre-scaled by log2(e) so attn can use exp2 directly.
__global__ __launch_bounds__(256) void cvt_xw(const float* __restrict__ x,
                                              const float* __restrict__ Wq,
                                              const float* __restrict__ Wk,
                                              const float* __restrict__ Wv,
                                              ushort* __restrict__ xb,
                                              ushort* __restrict__ wbt) {
  __shared__ ushort T[64 * 72];
  const int t = threadIdx.x;
  if (blockIdx.x < 4096) {
    int i = blockIdx.x * 256 + t;
    float4 v = ((const float4*)x)[i];
    ushort4 o;
    o.x = f2b(v.x); o.y = f2b(v.y); o.z = f2b(v.z); o.w = f2b(v.w);
    ((ushort4*)xb)[i] = o;
    return;
  }
  const int r = blockIdx.x - 4096;                // 0..767
  const int w = r >> 8, h = (r >> 4) & 15, d0 = (r & 15) * 64;
  const float* W = (w == 0) ? Wq : (w == 1) ? Wk : Wv;
  const float sc = (w == 0) ? 1.4426950408889634f : 1.0f;
  const float* src = W + (size_t)h * 65536 + (size_t)d0 * 64;   // [64 d][64 k]
#pragma unroll
  for (int j = 0; j < 4; ++j) {
    int idx = j * 256 + t;
    int dr = idx >> 4, kc = (idx & 15) * 4;
    float4 v = *(const float4*)(src + dr * 64 + kc);
    T[(kc + 0) * 72 + dr] = f2b(v.x * sc);
    T[(kc + 1) * 72 + dr] = f2b(v.y * sc);
    T[(kc + 2) * 72 + dr] = f2b(v.z * sc);
    T[(kc + 3) * 72 + dr] = f2b(v.w * sc);
  }
  __syncthreads();
  const int kk = t >> 2, dcg = (t & 3) * 16;
  ushort* dst = wbt + ((size_t)w * 1024 + h * 64 + kk) * 1024 + d0 + dcg;
  *(s8vec*)dst       = *(const s8vec*)&T[kk * 72 + dcg];
  *(s8vec*)(dst + 8) = *(const s8vec*)&T[kk * 72 + dcg + 8];
}

// ---- fused QKV projection: C[4096][3072] = X[4096][1024] @ Wbt^T (m97 structure) ----
__global__ __launch_bounds__(256) void proj_gemm(const ushort* __restrict__ xb,
                                                 const ushort* __restrict__ wbt,
                                                 ushort* __restrict__ qkv) {
  __shared__ __attribute__((aligned(16))) ushort As[128 * 64];
  __shared__ __attribute__((aligned(16))) ushort Bs[128 * 64];
  const int tid = threadIdx.x, wid = tid >> 6, lane = tid & 63;
  const int quad = lane >> 4, l15 = lane & 15;
  const int wm = wid & 1, wn = wid >> 1;
  const int m0 = blockIdx.x * 128, n0 = blockIdx.y * 128;

  f4vec acc[4][4];
#pragma unroll
  for (int mb = 0; mb < 4; mb++)
#pragma unroll
    for (int nb = 0; nb < 4; nb++)
#pragma unroll
      for (int i = 0; i < 4; i++) acc[mb][nb][i] = 0.f;

  const int sr = tid >> 3, sg = tid & 7;
  const int lg = sg ^ (sr & 7);
  const ushort* Ab = xb + (size_t)m0 * D_;
  const ushort* Bb = wbt + (size_t)n0 * D_;

  for (int k0 = 0; k0 < D_; k0 += 64) {
    __syncthreads();
#pragma unroll
    for (int j = 0; j < 4; ++j) {
      int r = j * 32 + sr;
      gl_lds16(Ab + (size_t)r * D_ + k0 + lg * 8, &As[j * 2048 + wid * 512]);
      gl_lds16(Bb + (size_t)r * D_ + k0 + lg * 8, &Bs[j * 2048 + wid * 512]);
    }
    __syncthreads();

#pragma unroll
    for (int kb = 0; kb < 2; ++kb) {
      s8vec af[4], bf[4];
#pragma unroll
      for (int mb = 0; mb < 4; ++mb) {
        int m = wm * 64 + mb * 16 + l15;
        int gpos = (kb * 4 + quad) ^ (m & 7);
        af[mb] = *(const s8vec*)&As[m * 64 + gpos * 8];
      }
#pragma unroll
      for (int nb = 0; nb < 4; ++nb) {
        int n = wn * 64 + nb * 16 + l15;
        int gpos = (kb * 4 + quad) ^ (n & 7);
        bf[nb] = *(const s8vec*)&Bs[n * 64 + gpos * 8];
      }
#pragma unroll
      for (int mb = 0; mb < 4; ++mb)
#pragma unroll
        for (int nb = 0; nb < 4; ++nb)
          acc[mb][nb] = mfma16(af[mb], bf[nb], acc[mb][nb]);
    }
  }

  const size_t per = (size_t)B_ * H_ * S_ * DK_;
  const int w = n0 >> 10;
  if (w == 2) {
    ushort* vt = qkv + 2 * per;
#pragma unroll
    for (int mb = 0; mb < 4; ++mb)
#pragma unroll
      for (int nb = 0; nb < 4; ++nb)
#pragma unroll
        for (int i = 0; i < 4; ++i) {
          int m = m0 + wm * 64 + mb * 16 + quad * 4 + i;
          int b = m >> 11, s = m & 2047;
          int n1 = (n0 & 1023) + wn * 64 + nb * 16 + l15;
          vt[((size_t)b * 1024 + n1) * S_ + s] = f2b(acc[mb][nb][i]);
        }
  } else {
#pragma unroll
    for (int mb = 0; mb < 4; ++mb)
#pragma unroll
      for (int nb = 0; nb < 4; ++nb)
#pragma unroll
        for (int i = 0; i < 4; ++i) {
          int m = m0 + wm * 64 + mb * 16 + quad * 4 + i;
          int b = m >> 11, s = m & 2047;
          int n1 = (n0 & 1023) + wn * 64 + nb * 16 + l15;
          qkv[(size_t)w * per + (((size_t)b * H_ + (n1 >> 6)) * S_ + s) * 64 + (n1 & 63)] =
              f2b(acc[mb][nb][i]);
        }
  }
}

// ---- flash attention v7: back to single-pass (KSPLIT=1, no merge) + in-wave
// software pipeline over the 4 x 32-key chunks of each tile.
// v6 lesson: residency is capped at ~2 blocks/CU by register footprint — TLP is
// a dead end; the 2300 cyc/chunk serial chain (LDS->QK->exp2->pack->PV) must be
// broken by ILP. Pipeline: LDAK(i+2) issue / QK(i+1) MFMAs (operands loaded a
// full iteration ago) / SM(i)+PV(i) VALU+MFMA overlap / LDAV(i+1).
// All s_setprio removed — the 16 setprio pairs per tile were scheduler fences
// that prevented any cross-phase interleave.
__global__ __launch_bounds__(256) void attn(const ushort* __restrict__ qg,
                                            const ushort* __restrict__ kg,
                                            const ushort* __restrict__ vtg,
                                            float* __restrict__ out) {
  __shared__ __attribute__((aligned(16))) ushort Ks[128 * 64];     // [key][d] swizzled
  __shared__ __attribute__((aligned(16))) ushort Vt[2][64 * 64];   // [half][dv][key] swizzled
  const int qt = blockIdx.x, bh = blockIdx.y;
  const int b = bh >> 4, h = bh & 15;
  const int tid = threadIdx.x, wid = tid >> 6, lane = tid & 63;
  const int quad = lane >> 4, l15 = lane & 15, l7 = l15 & 7;

  // Q B-fragments: 32 q-rows per wave (2 blocks of 16), loaded once.
  const ushort* qbase = qg + ((size_t)bh * S_ + qt * 128 + wid * 32) * DK_;
  s8vec bq[2][2];
#pragma unroll
  for (int qb = 0; qb < 2; ++qb)
#pragma unroll
    for (int kc = 0; kc < 2; ++kc)
      bq[qb][kc] = *(const s8vec*)(qbase + (size_t)(qb * 16 + l15) * DK_ + kc * 32 + quad * 8);

  f4vec o[4][2];            // O^T frags: [dv-block][q-block]
  float lsum[2] = {0.f, 0.f};
#pragma unroll
  for (int nb = 0; nb < 4; ++nb)
#pragma unroll
    for (int qb = 0; qb < 2; ++qb)
#pragma unroll
      for (int i = 0; i < 4; ++i) o[nb][qb][i] = 0.f;

  // staging: 256 threads stage 128x64 K + 64x128 V per tile.
  const int r5 = tid >> 3, gs = tid & 7;
  const int gk = gs ^ (r5 & 7);
  const ushort* kb_ = kg + (size_t)bh * S_ * DK_;
  const ushort* vb_ = vtg + (size_t)bh * 64 * S_;

  s8vec kr[4], vr[4];
#pragma unroll
  for (int j = 0; j < 4; ++j)
    kr[j] = *(const s8vec*)(kb_ + (size_t)(j * 32 + r5) * DK_ + gk * 8);
#pragma unroll
  for (int jd = 0; jd < 2; ++jd)
#pragma unroll
    for (int hf = 0; hf < 2; ++hf)
      vr[jd * 2 + hf] = *(const s8vec*)(vb_ + (size_t)(jd * 32 + r5) * S_ + hf * 64 + gk * 8);

// pipeline stage macros (all indices compile-time under full unroll)
#define LDAK(i, buf)                                                      \
  do {                                                                    \
    const int r0_ = ((i) * 2 + 0) * 16 + l15;                             \
    const int r1_ = ((i) * 2 + 1) * 16 + l15;                             \
    akb[buf][0] = *(const s8vec*)&Ks[r0_ * 64 + ((0 + quad) ^ l7) * 8];   \
    akb[buf][1] = *(const s8vec*)&Ks[r0_ * 64 + ((4 + quad) ^ l7) * 8];   \
    akb[buf][2] = *(const s8vec*)&Ks[r1_ * 64 + ((0 + quad) ^ l7) * 8];   \
    akb[buf][3] = *(const s8vec*)&Ks[r1_ * 64 + ((4 + quad) ^ l7) * 8];   \
  } while (0)

#define LDAV(i)                                                           \
  do {                                                                    \
    const int hf_ = (i) >> 1, G_ = ((i) & 1) * 4 + quad;                  \
    _Pragma("unroll")                                                     \
    for (int nb = 0; nb < 4; ++nb)                                        \
      avb[nb] = *(const s8vec*)&Vt[hf_][(nb * 16 + l15) * 64 + (G_ ^ l7) * 8]; \
  } while (0)

#define QKC(buf)                                                          \
  do {                                                                    \
    _Pragma("unroll")                                                     \
    for (int kbs = 0; kbs < 2; ++kbs)                                     \
      _Pragma("unroll")                                                   \
      for (int qb = 0; qb < 2; ++qb) {                                    \
        f4vec zz;                                                         \
        zz[0] = zz[1] = zz[2] = zz[3] = 0.f;                              \
        zz = mfma16(akb[buf][kbs * 2 + 0], bq[qb][0], zz);                \
        stb[buf][kbs][qb] = mfma16(akb[buf][kbs * 2 + 1], bq[qb][1], zz); \
      }                                                                   \
  } while (0)

#define SMPV(buf)                                                         \
  do {                                                                    \
    _Pragma("unroll")                                                     \
    for (int qb = 0; qb < 2; ++qb) {                                      \
      float p0 = exp2f_fast(stb[buf][0][qb][0]);                          \
      float p1 = exp2f_fast(stb[buf][0][qb][1]);                          \
      float p2 = exp2f_fast(stb[buf][0][qb][2]);                          \
      float p3 = exp2f_fast(stb[buf][0][qb][3]);                          \
      float p4 = exp2f_fast(stb[buf][1][qb][0]);                          \
      float p5 = exp2f_fast(stb[buf][1][qb][1]);                          \
      float p6 = exp2f_fast(stb[buf][1][qb][2]);                          \
      float p7 = exp2f_fast(stb[buf][1][qb][3]);                          \
      lsum[qb] += ((p0 + p1) + (p2 + p3)) + ((p4 + p5) + (p6 + p7));      \
      unsigned w0 = pk2(p0, p1), w1 = pk2(p2, p3);                        \
      unsigned w2 = pk2(p4, p5), w3 = pk2(p6, p7);                        \
      asm("v_permlane32_swap_b32 %0, %1" : "+v"(w0), "+v"(w2));           \
      asm("v_permlane16_swap_b32 %0, %1" : "+v"(w0), "+v"(w2));           \
      asm("v_permlane32_swap_b32 %0, %1" : "+v"(w1), "+v"(w3));           \
      asm("v_permlane16_swap_b32 %0, %1" : "+v"(w1), "+v"(w3));           \
      union { unsigned u[4]; s8vec v; } pb;                               \
      pb.u[0] = w0; pb.u[1] = w1; pb.u[2] = w2; pb.u[3] = w3;             \
      _Pragma("unroll")                                                   \
      for (int nb = 0; nb < 4; ++nb)                                      \
        o[nb][qb] = mfma16(avb[nb], pb.v, o[nb][qb]);                     \
    }                                                                     \
  } while (0)

  for (int kt = 0; kt < S_ / 128; ++kt) {
    wg_barrier_lds();                       // readers of previous tile done
#pragma unroll
    for (int j = 0; j < 4; ++j)             // vmcnt auto-waits these regs
      *(s8vec*)&Ks[(j * 32 + r5) * 64 + gs * 8] = kr[j];
#pragma unroll
    for (int jd = 0; jd < 2; ++jd)
#pragma unroll
      for (int hf = 0; hf < 2; ++hf)
        *(s8vec*)&Vt[hf][(jd * 32 + r5) * 64 + gs * 8] = vr[jd * 2 + hf];
    if (kt + 1 < S_ / 128) {                // prefetch next tile; stays in flight
      const ushort* kn = kb_ + (size_t)(kt + 1) * 128 * DK_;
#pragma unroll
      for (int j = 0; j < 4; ++j)
        kr[j] = *(const s8vec*)(kn + (size_t)(j * 32 + r5) * DK_ + gk * 8);
      const ushort* vn = vb_ + (kt + 1) * 128;
#pragma unroll
      for (int jd = 0; jd < 2; ++jd)
#pragma unroll
        for (int hf = 0; hf < 2; ++hf)
          vr[jd * 2 + hf] = *(const s8vec*)(vn + (size_t)(jd * 32 + r5) * S_ + hf * 64 + gk * 8);
    }
    wg_barrier_lds();                       // staging writes visible

    // software-pipelined 4 chunks of 32 keys
    s8vec akb[2][4];
    s8vec avb[4];
    f4vec stb[2][2][2];   // [buf][key-sub][q-block]

    LDAK(0, 0);
    LDAV(0);
    LDAK(1, 1);
    QKC(0);
#pragma unroll
    for (int i = 0; i < 4; ++i) {
      const int cur = i & 1, nxt = cur ^ 1;
      if (i < 2) LDAK(i + 2, cur);          // issue early; consumed 2 iters later
      if (i < 3) QKC(nxt);                  // MFMAs for chunk i+1 fill the pipe...
      SMPV(cur);                            // ...while VALU finishes chunk i
      if (i < 3) LDAV(i + 1);               // V frags for next chunk, hidden
    }
  }
#undef LDAK
#undef LDAV
#undef QKC
#undef SMPV

  // lsum: each lane has partial for q=qb*16+l15 over its keys; sum over quads.
  float inv[2];
#pragma unroll
  for (int qb = 0; qb < 2; ++qb) {
    float s = lsum[qb];
    s += __shfl_xor(s, 16, 64);
    s += __shfl_xor(s, 32, 64);
    inv[qb] = 1.0f / s;
  }

  // O^T[dv=nb*16+quad*4+i][q=qb*16+l15] -> out[b][s][h*64+dv]
  float* ob = out + ((size_t)b * S_ + qt * 128 + wid * 32) * D_ + h * DK_;
#pragma unroll
  for (int qb = 0; qb < 2; ++qb)
#pragma unroll
    for (int nb = 0; nb < 4; ++nb) {
      float4 vvv;
      vvv.x = o[nb][qb][0] * inv[qb];
      vvv.y = o[nb][qb][1] * inv[qb];
      vvv.z = o[nb][qb][2] * inv[qb];
      vvv.w = o[nb][qb][3] * inv[qb];
      *(float4*)&ob[(size_t)(qb * 16 + l15) * D_ + nb * 16 + quad * 4] = vvv;
    }
}

extern "C" void kernel_launch(void* const* d_in, const int* in_sizes, int n_in,
                              void* d_out, int out_size, void* d_ws, size_t ws_size,
                              hipStream_t stream) {
  const float* x  = (const float*)d_in[0];
  const float* Wq = (const float*)d_in[1];
  const float* Wk = (const float*)d_in[2];
  const float* Wv = (const float*)d_in[3];
  float* out = (float*)d_out;

  ushort* xb  = (ushort*)d_ws;                       // B*S*D bf16
  ushort* wbt = xb + (size_t)B_ * S_ * D_;           // [3072][1024] bf16
  ushort* qkv = wbt + (size_t)3 * D_ * D_;           // q,k: [b][h][s][64]; v: [b*1024+n1][s]
  const size_t per = (size_t)B_ * H_ * S_ * DK_;

  cvt_xw<<<4096 + 768, 256, 0, stream>>>(x, Wq, Wk, Wv, xb, wbt);
  proj_gemm<<<dim3(M_ / 128, N_ / 128), 256, 0, stream>>>(xb, wbt, qkv);
  attn<<<dim3(S_ / 128, B_ * H_), 256, 0, stream>>>(qkv, qkv + per, qkv + 2 * per, out);
}

// Round 5
// 166.807 us; speedup vs baseline: 1.8719x; 1.0479x over previous
//
#include <hip/hip_runtime.h>

#define B_ 2
#define S_ 2048
#define D_ 1024
#define H_ 16
#define DK_ 64
#define M_ (B_ * S_)   // 4096
#define N_ (3 * D_)    // 3072

typedef __bf16 bf16x8 __attribute__((ext_vector_type(8)));
typedef short s8vec __attribute__((ext_vector_type(8)));
typedef float f4vec __attribute__((ext_vector_type(4)));

static __device__ __forceinline__ ushort f2b(float f) {
  union { float f; unsigned u; } v; v.f = f;
  unsigned u = v.u;
  u += 0x7FFFu + ((u >> 16) & 1u);   // RNE to bf16
  return (ushort)(u >> 16);
}

static __device__ __forceinline__ unsigned pk2(float a, float b) {
#if __has_builtin(__builtin_amdgcn_cvt_pk_bf16_f32)
  typedef __bf16 b2 __attribute__((ext_vector_type(2)));
  b2 r = __builtin_amdgcn_cvt_pk_bf16_f32(a, b);
  return __builtin_bit_cast(unsigned, r);
#else
  return (unsigned)f2b(a) | ((unsigned)f2b(b) << 16);
#endif
}

static __device__ __forceinline__ float exp2f_fast(float x) {
#if __has_builtin(__builtin_amdgcn_exp2f)
  return __builtin_amdgcn_exp2f(x);
#else
  return __expf(x * 0.6931471805599453f);   // 2^x = e^(x ln2)
#endif
}

static __device__ __forceinline__ f4vec mfma16(s8vec a, s8vec b, f4vec c) {
  return __builtin_amdgcn_mfma_f32_16x16x32_bf16(
      __builtin_bit_cast(bf16x8, a), __builtin_bit_cast(bf16x8, b), c, 0, 0, 0);
}

static __device__ __forceinline__ void gl_lds16(const ushort* g, ushort* l) {
  __builtin_amdgcn_global_load_lds(
      (const __attribute__((address_space(1))) unsigned*)g,
      (__attribute__((address_space(3))) unsigned*)l, 16, 0, 0);
}

// raw workgroup barrier: drains LDS (lgkmcnt) only — in-flight GLOBAL loads to
// VGPRs stay outstanding across the barrier (the whole point of reg-prefetch).
// 0xC07F = vmcnt(63) expcnt(7) lgkmcnt(0). asm clobbers stop compiler reordering.
static __device__ __forceinline__ void wg_barrier_lds() {
  asm volatile("" ::: "memory");
  __builtin_amdgcn_s_waitcnt(0xC07F);
  __builtin_amdgcn_s_barrier();
  asm volatile("" ::: "memory");
}

// ---- fused input conversion: blocks [0,4096) convert x, [4096,4864) transpose W ----
// Wq (w==0) is pre-scaled by log2(e) so attn can use exp2 directly.
__global__ __launch_bounds__(256) void cvt_xw(const float* __restrict__ x,
                                              const float* __restrict__ Wq,
                                              const float* __restrict__ Wk,
                                              const float* __restrict__ Wv,
                                              ushort* __restrict__ xb,
                                              ushort* __restrict__ wbt) {
  __shared__ ushort T[64 * 72];
  const int t = threadIdx.x;
  if (blockIdx.x < 4096) {
    int i = blockIdx.x * 256 + t;
    float4 v = ((const float4*)x)[i];
    ushort4 o;
    o.x = f2b(v.x); o.y = f2b(v.y); o.z = f2b(v.z); o.w = f2b(v.w);
    ((ushort4*)xb)[i] = o;
    return;
  }
  const int r = blockIdx.x - 4096;                // 0..767
  const int w = r >> 8, h = (r >> 4) & 15, d0 = (r & 15) * 64;
  const float* W = (w == 0) ? Wq : (w == 1) ? Wk : Wv;
  const float sc = (w == 0) ? 1.4426950408889634f : 1.0f;
  const float* src = W + (size_t)h * 65536 + (size_t)d0 * 64;   // [64 d][64 k]
#pragma unroll
  for (int j = 0; j < 4; ++j) {
    int idx = j * 256 + t;
    int dr = idx >> 4, kc = (idx & 15) * 4;
    float4 v = *(const float4*)(src + dr * 64 + kc);
    T[(kc + 0) * 72 + dr] = f2b(v.x * sc);
    T[(kc + 1) * 72 + dr] = f2b(v.y * sc);
    T[(kc + 2) * 72 + dr] = f2b(v.z * sc);
    T[(kc + 3) * 72 + dr] = f2b(v.w * sc);
  }
  __syncthreads();
  const int kk = t >> 2, dcg = (t & 3) * 16;
  ushort* dst = wbt + ((size_t)w * 1024 + h * 64 + kk) * 1024 + d0 + dcg;
  *(s8vec*)dst       = *(const s8vec*)&T[kk * 72 + dcg];
  *(s8vec*)(dst + 8) = *(const s8vec*)&T[kk * 72 + dcg + 8];
}

// ---- fused QKV projection v8: C[4096][3072] = X[4096][1024] @ Wbt^T.
// 256x192 tile, BK=64, 512 thr (8 waves, 2m x 4n -> 128x48/wave, acc 8x3).
// Grid 16x16 = 256 blocks = exactly 1 block/CU (no tail).
// T3 minimum-2-phase: double-buffered LDS (112 KB), one __syncthreads per
// K-step (its implicit vmcnt(0)+lgkmcnt(0) drain is the only wait), next
// tile's global_load_lds issued BEFORE the current tile's MFMAs so HBM/L2
// latency hides under compute. Replaces the 2-barrier-per-step m97 loop
// (~450 TF at this short-K shape).
__global__ __launch_bounds__(512) void proj_gemm(const ushort* __restrict__ xb,
                                                 const ushort* __restrict__ wbt,
                                                 ushort* __restrict__ qkv) {
  __shared__ __attribute__((aligned(16))) ushort As[2][256 * 64];   // 2 x 32 KB
  __shared__ __attribute__((aligned(16))) ushort Bs[2][192 * 64];   // 2 x 24 KB
  const int tid = threadIdx.x, wid = tid >> 6, lane = tid & 63;
  const int quad = lane >> 4, l15 = lane & 15;
  const int wm = wid & 1, wn = wid >> 1;          // 2 m-halves x 4 n-quarters
  const int m0 = blockIdx.x * 256, n0 = blockIdx.y * 192;

  f4vec acc[8][3];
#pragma unroll
  for (int mb = 0; mb < 8; mb++)
#pragma unroll
    for (int nb = 0; nb < 3; nb++)
#pragma unroll
      for (int i = 0; i < 4; i++) acc[mb][nb][i] = 0.f;

  const int sr = tid >> 3, sg = tid & 7;          // sr 0..63: row-in-64-chunk
  const int gk = sg ^ (sr & 7);                   // swizzled source group
  const ushort* Ab = xb + (size_t)m0 * D_;
  const ushort* Bb = wbt + (size_t)n0 * D_;

// stage one K-tile into buf: A 256x64 (4 chunks), B 192x64 (3 chunks).
// LDS dest is wave-uniform base; lane writes base+l*16 -> row +(l>>3), unit l&7;
// source group gk = (l&7)^(row&7) gives LDS[row][u] = global group u^(row&7).
#define PSTAGE(buf, k0_)                                                    \
  do {                                                                      \
    _Pragma("unroll")                                                       \
    for (int j = 0; j < 4; ++j)                                             \
      gl_lds16(Ab + (size_t)(j * 64 + sr) * D_ + (k0_) + gk * 8,            \
               &As[buf][(j * 64 + wid * 8) * 64]);                          \
    _Pragma("unroll")                                                       \
    for (int j = 0; j < 3; ++j)                                             \
      gl_lds16(Bb + (size_t)(j * 64 + sr) * D_ + (k0_) + gk * 8,            \
               &Bs[buf][(j * 64 + wid * 8) * 64]);                          \
  } while (0)

#define PCOMP(buf)                                                          \
  do {                                                                      \
    _Pragma("unroll")                                                       \
    for (int kb = 0; kb < 2; ++kb) {                                        \
      s8vec af[8], bf[3];                                                   \
      _Pragma("unroll")                                                     \
      for (int mb = 0; mb < 8; ++mb) {                                      \
        int m = wm * 128 + mb * 16 + l15;                                   \
        int gpos = (kb * 4 + quad) ^ (m & 7);                               \
        af[mb] = *(const s8vec*)&As[buf][m * 64 + gpos * 8];                \
      }                                                                     \
      _Pragma("unroll")                                                     \
      for (int nb = 0; nb < 3; ++nb) {                                      \
        int n = wn * 48 + nb * 16 + l15;                                    \
        int gpos = (kb * 4 + quad) ^ (n & 7);                               \
        bf[nb] = *(const s8vec*)&Bs[buf][n * 64 + gpos * 8];                \
      }                                                                     \
      _Pragma("unroll")                                                     \
      for (int mb = 0; mb < 8; ++mb)                                        \
        _Pragma("unroll")                                                   \
        for (int nb = 0; nb < 3; ++nb)                                      \
          acc[mb][nb] = mfma16(af[mb], bf[nb], acc[mb][nb]);                \
    }                                                                       \
  } while (0)

  PSTAGE(0, 0);
  __syncthreads();                      // drain prologue loads
  for (int t = 0; t < 15; ++t) {
    const int cur = t & 1;
    PSTAGE(cur ^ 1, (t + 1) * 64);      // next tile in flight under MFMAs
    PCOMP(cur);
    __syncthreads();                    // implicit vmcnt(0): next buf ready;
  }                                     // all waves done reading cur
  PCOMP(1);                             // t=15 tile (staged in buf 1)
#undef PSTAGE
#undef PCOMP

  // epilogue: w = q/k/v selector per nb (BN=192 straddles 1024-boundaries)
  const size_t per = (size_t)B_ * H_ * S_ * DK_;
  ushort* vt = qkv + 2 * per;
#pragma unroll
  for (int mb = 0; mb < 8; ++mb)
#pragma unroll
    for (int nb = 0; nb < 3; ++nb) {
      const int n1g = n0 + wn * 48 + nb * 16 + l15;
      const int w = n1g >> 10, n1 = n1g & 1023;
      if (w == 2) {
#pragma unroll
        for (int i = 0; i < 4; ++i) {
          int m = m0 + wm * 128 + mb * 16 + quad * 4 + i;
          int b = m >> 11, s = m & 2047;
          vt[((size_t)b * 1024 + n1) * S_ + s] = f2b(acc[mb][nb][i]);
        }
      } else {
#pragma unroll
        for (int i = 0; i < 4; ++i) {
          int m = m0 + wm * 128 + mb * 16 + quad * 4 + i;
          int b = m >> 11, s = m & 2047;
          qkv[(size_t)w * per + (((size_t)b * H_ + (n1 >> 6)) * S_ + s) * 64 + (n1 & 63)] =
              f2b(acc[mb][nb][i]);
        }
      }
    }
}

// ---- flash attention (v7 structure, unchanged: 60.2 us verified) ----
__global__ __launch_bounds__(256) void attn(const ushort* __restrict__ qg,
                                            const ushort* __restrict__ kg,
                                            const ushort* __restrict__ vtg,
                                            float* __restrict__ out) {
  __shared__ __attribute__((aligned(16))) ushort Ks[128 * 64];     // [key][d] swizzled
  __shared__ __attribute__((aligned(16))) ushort Vt[2][64 * 64];   // [half][dv][key] swizzled
  const int qt = blockIdx.x, bh = blockIdx.y;
  const int b = bh >> 4, h = bh & 15;
  const int tid = threadIdx.x, wid = tid >> 6, lane = tid & 63;
  const int quad = lane >> 4, l15 = lane & 15, l7 = l15 & 7;

  // Q B-fragments: 32 q-rows per wave (2 blocks of 16), loaded once.
  const ushort* qbase = qg + ((size_t)bh * S_ + qt * 128 + wid * 32) * DK_;
  s8vec bq[2][2];
#pragma unroll
  for (int qb = 0; qb < 2; ++qb)
#pragma unroll
    for (int kc = 0; kc < 2; ++kc)
      bq[qb][kc] = *(const s8vec*)(qbase + (size_t)(qb * 16 + l15) * DK_ + kc * 32 + quad * 8);

  f4vec o[4][2];            // O^T frags: [dv-block][q-block]
  float lsum[2] = {0.f, 0.f};
#pragma unroll
  for (int nb = 0; nb < 4; ++nb)
#pragma unroll
    for (int qb = 0; qb < 2; ++qb)
#pragma unroll
      for (int i = 0; i < 4; ++i) o[nb][qb][i] = 0.f;

  // staging: 256 threads stage 128x64 K + 64x128 V per tile.
  const int r5 = tid >> 3, gs = tid & 7;
  const int gk = gs ^ (r5 & 7);
  const ushort* kb_ = kg + (size_t)bh * S_ * DK_;
  const ushort* vb_ = vtg + (size_t)bh * 64 * S_;

  s8vec kr[4], vr[4];
#pragma unroll
  for (int j = 0; j < 4; ++j)
    kr[j] = *(const s8vec*)(kb_ + (size_t)(j * 32 + r5) * DK_ + gk * 8);
#pragma unroll
  for (int jd = 0; jd < 2; ++jd)
#pragma unroll
    for (int hf = 0; hf < 2; ++hf)
      vr[jd * 2 + hf] = *(const s8vec*)(vb_ + (size_t)(jd * 32 + r5) * S_ + hf * 64 + gk * 8);

// pipeline stage macros (all indices compile-time under full unroll)
#define LDAK(i, buf)                                                      \
  do {                                                                    \
    const int r0_ = ((i) * 2 + 0) * 16 + l15;                             \
    const int r1_ = ((i) * 2 + 1) * 16 + l15;                             \
    akb[buf][0] = *(const s8vec*)&Ks[r0_ * 64 + ((0 + quad) ^ l7) * 8];   \
    akb[buf][1] = *(const s8vec*)&Ks[r0_ * 64 + ((4 + quad) ^ l7) * 8];   \
    akb[buf][2] = *(const s8vec*)&Ks[r1_ * 64 + ((0 + quad) ^ l7) * 8];   \
    akb[buf][3] = *(const s8vec*)&Ks[r1_ * 64 + ((4 + quad) ^ l7) * 8];   \
  } while (0)

#define LDAV(i)                                                           \
  do {                                                                    \
    const int hf_ = (i) >> 1, G_ = ((i) & 1) * 4 + quad;                  \
    _Pragma("unroll")                                                     \
    for (int nb = 0; nb < 4; ++nb)                                        \
      avb[nb] = *(const s8vec*)&Vt[hf_][(nb * 16 + l15) * 64 + (G_ ^ l7) * 8]; \
  } while (0)

#define QKC(buf)                                                          \
  do {                                                                    \
    _Pragma("unroll")                                                     \
    for (int kbs = 0; kbs < 2; ++kbs)                                     \
      _Pragma("unroll")                                                   \
      for (int qb = 0; qb < 2; ++qb) {                                    \
        f4vec zz;                                                         \
        zz[0] = zz[1] = zz[2] = zz[3] = 0.f;                              \
        zz = mfma16(akb[buf][kbs * 2 + 0], bq[qb][0], zz);                \
        stb[buf][kbs][qb] = mfma16(akb[buf][kbs * 2 + 1], bq[qb][1], zz); \
      }                                                                   \
  } while (0)

#define SMPV(buf)                                                         \
  do {                                                                    \
    _Pragma("unroll")                                                     \
    for (int qb = 0; qb < 2; ++qb) {                                      \
      float p0 = exp2f_fast(stb[buf][0][qb][0]);                          \
      float p1 = exp2f_fast(stb[buf][0][qb][1]);                          \
      float p2 = exp2f_fast(stb[buf][0][qb][2]);                          \
      float p3 = exp2f_fast(stb[buf][0][qb][3]);                          \
      float p4 = exp2f_fast(stb[buf][1][qb][0]);                          \
      float p5 = exp2f_fast(stb[buf][1][qb][1]);                          \
      float p6 = exp2f_fast(stb[buf][1][qb][2]);                          \
      float p7 = exp2f_fast(stb[buf][1][qb][3]);                          \
      lsum[qb] += ((p0 + p1) + (p2 + p3)) + ((p4 + p5) + (p6 + p7));      \
      unsigned w0 = pk2(p0, p1), w1 = pk2(p2, p3);                        \
      unsigned w2 = pk2(p4, p5), w3 = pk2(p6, p7);                        \
      asm("v_permlane32_swap_b32 %0, %1" : "+v"(w0), "+v"(w2));           \
      asm("v_permlane16_swap_b32 %0, %1" : "+v"(w0), "+v"(w2));           \
      asm("v_permlane32_swap_b32 %0, %1" : "+v"(w1), "+v"(w3));           \
      asm("v_permlane16_swap_b32 %0, %1" : "+v"(w1), "+v"(w3));           \
      union { unsigned u[4]; s8vec v; } pb;                               \
      pb.u[0] = w0; pb.u[1] = w1; pb.u[2] = w2; pb.u[3] = w3;             \
      _Pragma("unroll")                                                   \
      for (int nb = 0; nb < 4; ++nb)                                      \
        o[nb][qb] = mfma16(avb[nb], pb.v, o[nb][qb]);                     \
    }                                                                     \
  } while (0)

  for (int kt = 0; kt < S_ / 128; ++kt) {
    wg_barrier_lds();                       // readers of previous tile done
#pragma unroll
    for (int j = 0; j < 4; ++j)             // vmcnt auto-waits these regs
      *(s8vec*)&Ks[(j * 32 + r5) * 64 + gs * 8] = kr[j];
#pragma unroll
    for (int jd = 0; jd < 2; ++jd)
#pragma unroll
      for (int hf = 0; hf < 2; ++hf)
        *(s8vec*)&Vt[hf][(jd * 32 + r5) * 64 + gs * 8] = vr[jd * 2 + hf];
    if (kt + 1 < S_ / 128) {                // prefetch next tile; stays in flight
      const ushort* kn = kb_ + (size_t)(kt + 1) * 128 * DK_;
#pragma unroll
      for (int j = 0; j < 4; ++j)
        kr[j] = *(const s8vec*)(kn + (size_t)(j * 32 + r5) * DK_ + gk * 8);
      const ushort* vn = vb_ + (kt + 1) * 128;
#pragma unroll
      for (int jd = 0; jd < 2; ++jd)
#pragma unroll
        for (int hf = 0; hf < 2; ++hf)
          vr[jd * 2 + hf] = *(const s8vec*)(vn + (size_t)(jd * 32 + r5) * S_ + hf * 64 + gk * 8);
    }
    wg_barrier_lds();                       // staging writes visible

    // software-pipelined 4 chunks of 32 keys
    s8vec akb[2][4];
    s8vec avb[4];
    f4vec stb[2][2][2];   // [buf][key-sub][q-block]

    LDAK(0, 0);
    LDAV(0);
    LDAK(1, 1);
    QKC(0);
#pragma unroll
    for (int i = 0; i < 4; ++i) {
      const int cur = i & 1, nxt = cur ^ 1;
      if (i < 2) LDAK(i + 2, cur);          // issue early; consumed 2 iters later
      if (i < 3) QKC(nxt);                  // MFMAs for chunk i+1 fill the pipe...
      SMPV(cur);                            // ...while VALU finishes chunk i
      if (i < 3) LDAV(i + 1);               // V frags for next chunk, hidden
    }
  }
#undef LDAK
#undef LDAV
#undef QKC
#undef SMPV

  // lsum: each lane has partial for q=qb*16+l15 over its keys; sum over quads.
  float inv[2];
#pragma unroll
  for (int qb = 0; qb < 2; ++qb) {
    float s = lsum[qb];
    s += __shfl_xor(s, 16, 64);
    s += __shfl_xor(s, 32, 64);
    inv[qb] = 1.0f / s;
  }

  // O^T[dv=nb*16+quad*4+i][q=qb*16+l15] -> out[b][s][h*64+dv]
  float* ob = out + ((size_t)b * S_ + qt * 128 + wid * 32) * D_ + h * DK_;
#pragma unroll
  for (int qb = 0; qb < 2; ++qb)
#pragma unroll
    for (int nb = 0; nb < 4; ++nb) {
      float4 vvv;
      vvv.x = o[nb][qb][0] * inv[qb];
      vvv.y = o[nb][qb][1] * inv[qb];
      vvv.z = o[nb][qb][2] * inv[qb];
      vvv.w = o[nb][qb][3] * inv[qb];
      *(float4*)&ob[(size_t)(qb * 16 + l15) * D_ + nb * 16 + quad * 4] = vvv;
    }
}

extern "C" void kernel_launch(void* const* d_in, const int* in_sizes, int n_in,
                              void* d_out, int out_size, void* d_ws, size_t ws_size,
                              hipStream_t stream) {
  const float* x  = (const float*)d_in[0];
  const float* Wq = (const float*)d_in[1];
  const float* Wk = (const float*)d_in[2];
  const float* Wv = (const float*)d_in[3];
  float* out = (float*)d_out;

  ushort* xb  = (ushort*)d_ws;                       // B*S*D bf16
  ushort* wbt = xb + (size_t)B_ * S_ * D_;           // [3072][1024] bf16
  ushort* qkv = wbt + (size_t)3 * D_ * D_;           // q,k: [b][h][s][64]; v: [b*1024+n1][s]
  const size_t per = (size_t)B_ * H_ * S_ * DK_;

  cvt_xw<<<4096 + 768, 256, 0, stream>>>(x, Wq, Wk, Wv, xb, wbt);
  proj_gemm<<<dim3(M_ / 256, N_ / 192), 512, 0, stream>>>(xb, wbt, qkv);
  attn<<<dim3(S_ / 128, B_ * H_), 256, 0, stream>>>(qkv, qkv + per, qkv + 2 * per, out);
}

// Round 6
// 162.160 us; speedup vs baseline: 1.9256x; 1.0287x over previous
//
#include <hip/hip_runtime.h>

#define B_ 2
#define S_ 2048
#define D_ 1024
#define H_ 16
#define DK_ 64
#define M_ (B_ * S_)   // 4096
#define N_ (3 * D_)    // 3072

typedef __bf16 bf16x8 __attribute__((ext_vector_type(8)));
typedef short s8vec __attribute__((ext_vector_type(8)));
typedef float f4vec __attribute__((ext_vector_type(4)));
typedef float f16vec __attribute__((ext_vector_type(16)));

static __device__ __forceinline__ ushort f2b(float f) {
  union { float f; unsigned u; } v; v.f = f;
  unsigned u = v.u;
  u += 0x7FFFu + ((u >> 16) & 1u);   // RNE to bf16
  return (ushort)(u >> 16);
}

static __device__ __forceinline__ unsigned pk2(float a, float b) {
#if __has_builtin(__builtin_amdgcn_cvt_pk_bf16_f32)
  typedef __bf16 b2 __attribute__((ext_vector_type(2)));
  b2 r = __builtin_amdgcn_cvt_pk_bf16_f32(a, b);
  return __builtin_bit_cast(unsigned, r);
#else
  return (unsigned)f2b(a) | ((unsigned)f2b(b) << 16);
#endif
}

static __device__ __forceinline__ float exp2f_fast(float x) {
#if __has_builtin(__builtin_amdgcn_exp2f)
  return __builtin_amdgcn_exp2f(x);
#else
  return __expf(x * 0.6931471805599453f);   // 2^x = e^(x ln2)
#endif
}

static __device__ __forceinline__ f4vec mfma16(s8vec a, s8vec b, f4vec c) {
  return __builtin_amdgcn_mfma_f32_16x16x32_bf16(
      __builtin_bit_cast(bf16x8, a), __builtin_bit_cast(bf16x8, b), c, 0, 0, 0);
}

static __device__ __forceinline__ f16vec mfma32(s8vec a, s8vec b, f16vec c) {
  return __builtin_amdgcn_mfma_f32_32x32x16_bf16(
      __builtin_bit_cast(bf16x8, a), __builtin_bit_cast(bf16x8, b), c, 0, 0, 0);
}

static __device__ __forceinline__ void gl_lds16(const ushort* g, ushort* l) {
  __builtin_amdgcn_global_load_lds(
      (const __attribute__((address_space(1))) unsigned*)g,
      (__attribute__((address_space(3))) unsigned*)l, 16, 0, 0);
}

// raw workgroup barrier: drains LDS (lgkmcnt) only — in-flight GLOBAL loads to
// VGPRs stay outstanding across the barrier (the whole point of reg-prefetch).
static __device__ __forceinline__ void wg_barrier_lds() {
  asm volatile("" ::: "memory");
  __builtin_amdgcn_s_waitcnt(0xC07F);
  __builtin_amdgcn_s_barrier();
  asm volatile("" ::: "memory");
}

// ---- fused input conversion: blocks [0,4096) convert x, [4096,4864) transpose W ----
// Wq (w==0) is pre-scaled by log2(e) so attn can use exp2 directly.
__global__ __launch_bounds__(256) void cvt_xw(const float* __restrict__ x,
                                              const float* __restrict__ Wq,
                                              const float* __restrict__ Wk,
                                              const float* __restrict__ Wv,
                                              ushort* __restrict__ xb,
                                              ushort* __restrict__ wbt) {
  __shared__ ushort T[64 * 72];
  const int t = threadIdx.x;
  if (blockIdx.x < 4096) {
    int i = blockIdx.x * 256 + t;
    float4 v = ((const float4*)x)[i];
    ushort4 o;
    o.x = f2b(v.x); o.y = f2b(v.y); o.z = f2b(v.z); o.w = f2b(v.w);
    ((ushort4*)xb)[i] = o;
    return;
  }
  const int r = blockIdx.x - 4096;                // 0..767
  const int w = r >> 8, h = (r >> 4) & 15, d0 = (r & 15) * 64;
  const float* W = (w == 0) ? Wq : (w == 1) ? Wk : Wv;
  const float sc = (w == 0) ? 1.4426950408889634f : 1.0f;
  const float* src = W + (size_t)h * 65536 + (size_t)d0 * 64;   // [64 d][64 k]
#pragma unroll
  for (int j = 0; j < 4; ++j) {
    int idx = j * 256 + t;
    int dr = idx >> 4, kc = (idx & 15) * 4;
    float4 v = *(const float4*)(src + dr * 64 + kc);
    T[(kc + 0) * 72 + dr] = f2b(v.x * sc);
    T[(kc + 1) * 72 + dr] = f2b(v.y * sc);
    T[(kc + 2) * 72 + dr] = f2b(v.z * sc);
    T[(kc + 3) * 72 + dr] = f2b(v.w * sc);
  }
  __syncthreads();
  const int kk = t >> 2, dcg = (t & 3) * 16;
  ushort* dst = wbt + ((size_t)w * 1024 + h * 64 + kk) * 1024 + d0 + dcg;
  *(s8vec*)dst       = *(const s8vec*)&T[kk * 72 + dcg];
  *(s8vec*)(dst + 8) = *(const s8vec*)&T[kk * 72 + dcg + 8];
}

// ---- fused QKV projection v8 (unchanged from round 5): 256x192 tile, BK=64,
// 512 thr, 2-phase double-buffered LDS, 1 block/CU ----
__global__ __launch_bounds__(512) void proj_gemm(const ushort* __restrict__ xb,
                                                 const ushort* __restrict__ wbt,
                                                 ushort* __restrict__ qkv) {
  __shared__ __attribute__((aligned(16))) ushort As[2][256 * 64];
  __shared__ __attribute__((aligned(16))) ushort Bs[2][192 * 64];
  const int tid = threadIdx.x, wid = tid >> 6, lane = tid & 63;
  const int quad = lane >> 4, l15 = lane & 15;
  const int wm = wid & 1, wn = wid >> 1;
  const int m0 = blockIdx.x * 256, n0 = blockIdx.y * 192;

  f4vec acc[8][3];
#pragma unroll
  for (int mb = 0; mb < 8; mb++)
#pragma unroll
    for (int nb = 0; nb < 3; nb++)
#pragma unroll
      for (int i = 0; i < 4; i++) acc[mb][nb][i] = 0.f;

  const int sr = tid >> 3, sg = tid & 7;
  const int gk = sg ^ (sr & 7);
  const ushort* Ab = xb + (size_t)m0 * D_;
  const ushort* Bb = wbt + (size_t)n0 * D_;

#define PSTAGE(buf, k0_)                                                    \
  do {                                                                      \
    _Pragma("unroll")                                                       \
    for (int j = 0; j < 4; ++j)                                             \
      gl_lds16(Ab + (size_t)(j * 64 + sr) * D_ + (k0_) + gk * 8,            \
               &As[buf][(j * 64 + wid * 8) * 64]);                          \
    _Pragma("unroll")                                                       \
    for (int j = 0; j < 3; ++j)                                             \
      gl_lds16(Bb + (size_t)(j * 64 + sr) * D_ + (k0_) + gk * 8,            \
               &Bs[buf][(j * 64 + wid * 8) * 64]);                          \
  } while (0)

#define PCOMP(buf)                                                          \
  do {                                                                      \
    _Pragma("unroll")                                                       \
    for (int kb = 0; kb < 2; ++kb) {                                        \
      s8vec af[8], bf[3];                                                   \
      _Pragma("unroll")                                                     \
      for (int mb = 0; mb < 8; ++mb) {                                      \
        int m = wm * 128 + mb * 16 + l15;                                   \
        int gpos = (kb * 4 + quad) ^ (m & 7);                               \
        af[mb] = *(const s8vec*)&As[buf][m * 64 + gpos * 8];                \
      }                                                                     \
      _Pragma("unroll")                                                     \
      for (int nb = 0; nb < 3; ++nb) {                                      \
        int n = wn * 48 + nb * 16 + l15;                                    \
        int gpos = (kb * 4 + quad) ^ (n & 7);                               \
        bf[nb] = *(const s8vec*)&Bs[buf][n * 64 + gpos * 8];                \
      }                                                                     \
      _Pragma("unroll")                                                     \
      for (int mb = 0; mb < 8; ++mb)                                        \
        _Pragma("unroll")                                                   \
        for (int nb = 0; nb < 3; ++nb)                                      \
          acc[mb][nb] = mfma16(af[mb], bf[nb], acc[mb][nb]);                \
    }                                                                       \
  } while (0)

  PSTAGE(0, 0);
  __syncthreads();
  for (int t = 0; t < 15; ++t) {
    const int cur = t & 1;
    PSTAGE(cur ^ 1, (t + 1) * 64);
    PCOMP(cur);
    __syncthreads();
  }
  PCOMP(1);
#undef PSTAGE
#undef PCOMP

  const size_t per = (size_t)B_ * H_ * S_ * DK_;
  ushort* vt = qkv + 2 * per;
#pragma unroll
  for (int mb = 0; mb < 8; ++mb)
#pragma unroll
    for (int nb = 0; nb < 3; ++nb) {
      const int n1g = n0 + wn * 48 + nb * 16 + l15;
      const int w = n1g >> 10, n1 = n1g & 1023;
      if (w == 2) {
#pragma unroll
        for (int i = 0; i < 4; ++i) {
          int m = m0 + wm * 128 + mb * 16 + quad * 4 + i;
          int b = m >> 11, s = m & 2047;
          vt[((size_t)b * 1024 + n1) * S_ + s] = f2b(acc[mb][nb][i]);
        }
      } else {
#pragma unroll
        for (int i = 0; i < 4; ++i) {
          int m = m0 + wm * 128 + mb * 16 + quad * 4 + i;
          int b = m >> 11, s = m & 2047;
          qkv[(size_t)w * per + (((size_t)b * H_ + (n1 >> 6)) * S_ + s) * 64 + (n1 & 63)] =
              f2b(acc[mb][nb][i]);
        }
      }
    }
}

// ---- flash attention v9: fat waves. Q-tile 256, 512 thr = 8 waves
// (4 q-groups x 2 key-halves), 32x32x16 MFMAs. Grid (8,32) = 256 blocks = 1/CU.
// Rationale: occupancy is capped at 2 waves/SIMD by wave count (v6), VGPRs are
// underused (108/256) — so amortize LDS reads over 2x q per wave and use the
// denser MFMA shape. Per-CU LDS traffic per tile halves (320->160 KB); MFMA
// floor ~14.5 us. Key-halves hold disjoint keys; no-max softmax partials are
// additive -> merged once at epilogue via 32 KB LDS (aliased over dead Ks/Vt).
// Layouts: 32x32 C-map col=l&31,row=(r&3)+8*(r>>2)+4*(l>>5) [HW-verified];
// A/B frags k=8*(l>>5)+reg; P->B-frag via 2 permlane32_swap per 16-key window.
__global__ __launch_bounds__(512) void attn(const ushort* __restrict__ qg,
                                            const ushort* __restrict__ kg,
                                            const ushort* __restrict__ vtg,
                                            float* __restrict__ out) {
  // pooled LDS: Ks 128x64 (16KB) + Vt 2x64x64 (16KB); epilogue aliases the
  // same 32KB as OM (2 q-groups per round x 4096 floats).
  __shared__ __attribute__((aligned(16))) ushort KV[128 * 64 + 2 * 64 * 64];
  __shared__ float LM[4][64];
  ushort* Ks  = KV;
  ushort* Vt0 = KV + 128 * 64;          // Vt[hf] = Vt0 + hf*4096
  float*  OM  = (float*)KV;

  const int qt = blockIdx.x, bh = blockIdx.y;
  const int b = bh >> 4, h = bh & 15;
  const int tid = threadIdx.x, wid = tid >> 6, lane = tid & 63;
  const int l31 = lane & 31, hi = lane >> 5, l7 = lane & 7;
  const int qgi = wid >> 1, kh = wid & 1;   // q-group 0..3, key-half 0..1

  // Q B-frags: 64 q rows (2 subtiles of 32), 4 d-slices of 16.
  // B layout: col=q=l31, k = s*16 + 8*hi + r.
  const ushort* qb = qg + ((size_t)bh * S_ + qt * 256 + qgi * 64) * DK_;
  s8vec bq[2][4];
#pragma unroll
  for (int qs = 0; qs < 2; ++qs)
#pragma unroll
    for (int s = 0; s < 4; ++s)
      bq[qs][s] = *(const s8vec*)(qb + (size_t)(qs * 32 + l31) * DK_ + s * 16 + hi * 8);

  f16vec o[2][2];           // O^T accum: [dv-half][q-subtile], 32x32 C each
  float lsum[2] = {0.f, 0.f};
#pragma unroll
  for (int dvh = 0; dvh < 2; ++dvh)
#pragma unroll
    for (int qs = 0; qs < 2; ++qs)
#pragma unroll
      for (int i = 0; i < 16; ++i) o[dvh][qs][i] = 0.f;

  // staging: 512 threads stage K 128x64 + V 64x128 per tile (4 loads/thread).
  const int r6 = tid >> 3, gs = tid & 7;        // r6 0..63, group 0..7
  const int gk = gs ^ (r6 & 7);
  const ushort* kb_ = kg + (size_t)bh * S_ * DK_;
  const ushort* vb_ = vtg + (size_t)bh * 64 * S_ + (size_t)r6 * S_;

  s8vec kr[2], vr[2];
  kr[0] = *(const s8vec*)(kb_ + (size_t)r6 * DK_ + gk * 8);
  kr[1] = *(const s8vec*)(kb_ + (size_t)(64 + r6) * DK_ + gk * 8);
  vr[0] = *(const s8vec*)(vb_ + gk * 8);
  vr[1] = *(const s8vec*)(vb_ + 64 + gk * 8);

  for (int kt = 0; kt < S_ / 128; ++kt) {
    wg_barrier_lds();                       // readers of previous tile done
    *(s8vec*)&Ks[r6 * 64 + gs * 8]        = kr[0];
    *(s8vec*)&Ks[(64 + r6) * 64 + gs * 8] = kr[1];
    *(s8vec*)&Vt0[r6 * 64 + gs * 8]       = vr[0];
    *(s8vec*)&Vt0[4096 + r6 * 64 + gs * 8] = vr[1];
    if (kt + 1 < S_ / 128) {                // prefetch next tile
      const ushort* kn = kb_ + (size_t)(kt + 1) * 128 * DK_;
      kr[0] = *(const s8vec*)(kn + (size_t)r6 * DK_ + gk * 8);
      kr[1] = *(const s8vec*)(kn + (size_t)(64 + r6) * DK_ + gk * 8);
      const ushort* vn = vb_ + (kt + 1) * 128;
      vr[0] = *(const s8vec*)(vn + gk * 8);
      vr[1] = *(const s8vec*)(vn + 64 + gk * 8);
    }
    wg_barrier_lds();                       // staging writes visible

    // this wave: keys [kh*64, kh*64+64) as 2 chunks of 32, for 64 q
#pragma unroll
    for (int c = 0; c < 2; ++c) {
      const int row0 = kh * 64 + c * 32 + l31;    // key row; row0&7 == l7
      s8vec ak[4];
#pragma unroll
      for (int s = 0; s < 4; ++s)
        ak[s] = *(const s8vec*)&Ks[row0 * 64 + (((2 * s + hi)) ^ l7) * 8];

      f16vec st[2];
#pragma unroll
      for (int qs = 0; qs < 2; ++qs)
#pragma unroll
        for (int i = 0; i < 16; ++i) st[qs][i] = 0.f;
#pragma unroll
      for (int s = 0; s < 4; ++s) {
        st[0] = mfma32(ak[s], bq[0][s], st[0]);
        st[1] = mfma32(ak[s], bq[1][s], st[1]);
      }

#pragma unroll
      for (int qs = 0; qs < 2; ++qs) {
        float p[16];
#pragma unroll
        for (int r = 0; r < 16; ++r) p[r] = exp2f_fast(st[qs][r]);
        float s0 = ((p[0] + p[1]) + (p[2] + p[3])) + ((p[4] + p[5]) + (p[6] + p[7]));
        float s1 = ((p[8] + p[9]) + (p[10] + p[11])) + ((p[12] + p[13]) + (p[14] + p[15]));
        lsum[qs] += s0 + s1;
        // per 16-key window m: build PV B-frag (k = 8*hi + 0..7, col = q)
#pragma unroll
        for (int m = 0; m < 2; ++m) {
          unsigned u01 = pk2(p[m * 8 + 0], p[m * 8 + 1]);   // keys {0,1}+4hi
          unsigned u23 = pk2(p[m * 8 + 2], p[m * 8 + 3]);   // keys {2,3}+4hi
          unsigned u89 = pk2(p[m * 8 + 4], p[m * 8 + 5]);   // keys {8,9}+4hi
          unsigned uAB = pk2(p[m * 8 + 6], p[m * 8 + 7]);   // keys {10,11}+4hi
          // swap32: a'=[a.lo|b.lo], b'=[a.hi|b.hi]
          asm("v_permlane32_swap_b32 %0, %1" : "+v"(u01), "+v"(u89));
          asm("v_permlane32_swap_b32 %0, %1" : "+v"(u23), "+v"(uAB));
          union { unsigned u[4]; s8vec v; } pb;
          pb.u[0] = u01;   // w0: [{0,1}|{8,9}]
          pb.u[1] = u23;   // w1: [{2,3}|{10,11}]
          pb.u[2] = u89;   // w2: [{4,5}|{12,13}]
          pb.u[3] = uAB;   // w3: [{6,7}|{14,15}]
#pragma unroll
          for (int dvh = 0; dvh < 2; ++dvh) {
            s8vec av = *(const s8vec*)&Vt0[kh * 4096 + (dvh * 32 + l31) * 64 +
                                           ((4 * c + 2 * m + hi) ^ l7) * 8];
            o[dvh][qs] = mfma32(av, pb.v, o[dvh][qs]);
          }
        }
      }
    }
  }

  // per-q partial sum over this wave's key-half (hi-halves hold disjoint keys)
#pragma unroll
  for (int qs = 0; qs < 2; ++qs) lsum[qs] += __shfl_xor(lsum[qs], 32, 64);

  // merge key-halves: kh=1 waves publish via LDS (aliased over Ks/Vt),
  // kh=0 waves combine + normalize + write. 2 rounds of 2 q-groups (32 KB).
  __syncthreads();
#pragma unroll
  for (int rnd = 0; rnd < 2; ++rnd) {
    if (kh == 1 && (qgi >> 1) == rnd) {
      const int slot = (qgi & 1) * 4;
#pragma unroll
      for (int dvh = 0; dvh < 2; ++dvh)
#pragma unroll
        for (int qs = 0; qs < 2; ++qs)
#pragma unroll
          for (int r = 0; r < 16; ++r)
            OM[(slot + dvh * 2 + qs) * 1024 + r * 64 + lane] = o[dvh][qs][r];
      if (!hi) {
        LM[qgi][l31]      = lsum[0];
        LM[qgi][32 + l31] = lsum[1];
      }
    }
    __syncthreads();
    if (kh == 0 && (qgi >> 1) == rnd) {
      const int slot = (qgi & 1) * 4;
      float linv[2];
#pragma unroll
      for (int qs = 0; qs < 2; ++qs)
        linv[qs] = 1.0f / (lsum[qs] + LM[qgi][qs * 32 + l31]);
      float* ob = out + ((size_t)b * S_ + qt * 256 + qgi * 64) * D_ + h * DK_;
#pragma unroll
      for (int dvh = 0; dvh < 2; ++dvh)
#pragma unroll
        for (int qs = 0; qs < 2; ++qs)
#pragma unroll
          for (int qd = 0; qd < 4; ++qd) {
            float4 vv;
            vv.x = (o[dvh][qs][qd * 4 + 0] +
                    OM[(slot + dvh * 2 + qs) * 1024 + (qd * 4 + 0) * 64 + lane]) * linv[qs];
            vv.y = (o[dvh][qs][qd * 4 + 1] +
                    OM[(slot + dvh * 2 + qs) * 1024 + (qd * 4 + 1) * 64 + lane]) * linv[qs];
            vv.z = (o[dvh][qs][qd * 4 + 2] +
                    OM[(slot + dvh * 2 + qs) * 1024 + (qd * 4 + 2) * 64 + lane]) * linv[qs];
            vv.w = (o[dvh][qs][qd * 4 + 3] +
                    OM[(slot + dvh * 2 + qs) * 1024 + (qd * 4 + 3) * 64 + lane]) * linv[qs];
            // dv = dvh*32 + qd*8 + 4*hi + {0..3}
            *(float4*)&ob[(size_t)(qs * 32 + l31) * D_ + dvh * 32 + qd * 8 + 4 * hi] = vv;
          }
    }
    __syncthreads();
  }
}

extern "C" void kernel_launch(void* const* d_in, const int* in_sizes, int n_in,
                              void* d_out, int out_size, void* d_ws, size_t ws_size,
                              hipStream_t stream) {
  const float* x  = (const float*)d_in[0];
  const float* Wq = (const float*)d_in[1];
  const float* Wk = (const float*)d_in[2];
  const float* Wv = (const float*)d_in[3];
  float* out = (float*)d_out;

  ushort* xb  = (ushort*)d_ws;                       // B*S*D bf16
  ushort* wbt = xb + (size_t)B_ * S_ * D_;           // [3072][1024] bf16
  ushort* qkv = wbt + (size_t)3 * D_ * D_;           // q,k: [b][h][s][64]; v: [b*1024+n1][s]
  const size_t per = (size_t)B_ * H_ * S_ * DK_;

  cvt_xw<<<4096 + 768, 256, 0, stream>>>(x, Wq, Wk, Wv, xb, wbt);
  proj_gemm<<<dim3(M_ / 256, N_ / 192), 512, 0, stream>>>(xb, wbt, qkv);
  attn<<<dim3(S_ / 256, B_ * H_), 512, 0, stream>>>(qkv, qkv + per, qkv + 2 * per, out);
}